// Round 6
// baseline (2456.287 us; speedup 1.0000x reference)
//
#include <hip/hip_runtime.h>
#include <hip/hip_bf16.h>

// ---------------------------------------------------------------------------
// PointNet++ critic forward. fp32. B=32, N=4096.
// R6: dense layers stage weight chunks (8KB) in LDS with 2-reg prefetch
// double-buffer; all waves share one copy (kills the 8x-redundant per-thread
// global weight stream that exceeded per-CU L2 BW). Layer-3 row-blocks merged
// (persistent acc) so O=256 weights are read once per cc.
// ---------------------------------------------------------------------------

// ======================= DPP wave64 max-reduce (u64) =======================
template<int CTRL>
__device__ __forceinline__ unsigned long long dpp_mov_u64(unsigned long long x) {
    const int lo = (int)(unsigned)(x & 0xffffffffull);
    const int hi = (int)(unsigned)(x >> 32);
    const int nlo = __builtin_amdgcn_update_dpp(lo, lo, CTRL, 0xf, 0xf, false);
    const int nhi = __builtin_amdgcn_update_dpp(hi, hi, CTRL, 0xf, 0xf, false);
    return ((unsigned long long)(unsigned)nhi << 32) | (unsigned)nlo;
}

__device__ __forceinline__ unsigned long long wave_max_u64(unsigned long long x) {
    unsigned long long y;
    y = dpp_mov_u64<0x111>(x); if (y > x) x = y;   // row_shr:1
    y = dpp_mov_u64<0x112>(x); if (y > x) x = y;   // row_shr:2
    y = dpp_mov_u64<0x114>(x); if (y > x) x = y;   // row_shr:4
    y = dpp_mov_u64<0x118>(x); if (y > x) x = y;   // row_shr:8
    y = dpp_mov_u64<0x142>(x); if (y > x) x = y;   // row_bcast:15
    y = dpp_mov_u64<0x143>(x); if (y > x) x = y;   // row_bcast:31
    return x;
}

// ============================ FPS ==========================================
template<int N, int S, int NT, bool CHW>
__global__ __launch_bounds__(NT)
void fps_kernel(const float* __restrict__ xyz, float* __restrict__ new_xyz) {
    constexpr int P  = N / NT;
    constexpr int NW = NT / 64;
    __shared__ __align__(16) float4 sxyz[N];
    __shared__ __align__(16) unsigned long long rv[2][NW > 1 ? NW : 2];
    const int b = blockIdx.x, t = threadIdx.x;
    float px[P], py[P], pz[P], dist[P];
    if (CHW) {
        const float* base = xyz + (size_t)b * 3 * N;
        #pragma unroll
        for (int p = 0; p < P; ++p) {
            const int i = p * NT + t;
            px[p] = base[i]; py[p] = base[N + i]; pz[p] = base[2 * N + i];
            sxyz[i] = make_float4(px[p], py[p], pz[p], 0.0f);
        }
    } else {
        const float* base = xyz + (size_t)b * N * 3;
        #pragma unroll
        for (int p = 0; p < P; ++p) {
            const int i = p * NT + t;
            px[p] = base[i*3]; py[p] = base[i*3+1]; pz[p] = base[i*3+2];
            sxyz[i] = make_float4(px[p], py[p], pz[p], 0.0f);
        }
    }
    #pragma unroll
    for (int p = 0; p < P; ++p) dist[p] = 1e10f;
    __syncthreads();
    int far = 0;
    float* out = new_xyz + (size_t)b * S * 3;
    for (int j = 0; j < S; ++j) {
        const float4 cen = sxyz[far];            // broadcast b128
        if (t == 0) { out[j*3+0] = cen.x; out[j*3+1] = cen.y; out[j*3+2] = cen.z; }
        float bv = -1.0f; int bi = 0;
        #pragma unroll
        for (int p = 0; p < P; ++p) {
            const int i = p * NT + t;
            const float dx = px[p] - cen.x, dy = py[p] - cen.y, dz = pz[p] - cen.z;
            // match reference rounding exactly: no FMA contraction
            const float d = __fadd_rn(__fadd_rn(__fmul_rn(dx, dx), __fmul_rn(dy, dy)), __fmul_rn(dz, dz));
            const float nd = fminf(dist[p], d);
            dist[p] = nd;
            if (nd > bv) { bv = nd; bi = i; }    // strict > keeps smallest i
        }
        unsigned long long pk =
            ((unsigned long long)__float_as_uint(bv) << 32) | (unsigned)(N - 1 - bi);
        pk = wave_max_u64(pk);
        if constexpr (NW > 1) {
            const int sl = j & 1;
            if ((t & 63) == 63) rv[sl][t >> 6] = pk;
            __syncthreads();
            unsigned long long best = rv[sl][0];
            #pragma unroll
            for (int w = 1; w < NW; ++w) { const unsigned long long v = rv[sl][w]; if (v > best) best = v; }
            far = N - 1 - (int)(best & 0xffffffffull);
        } else {
            far = N - 1 - __builtin_amdgcn_readlane((int)(pk & 0xffffffffull), 63);
        }
    }
}

// ============================ Ball query ===================================
template<int N, int NS, bool CHW, int NT>
__global__ __launch_bounds__(NT)
void bq_kernel(float r2, const float* __restrict__ xyz, const float* __restrict__ cen,
               int* __restrict__ gidx, int S) {
    constexpr int WPB = NT / 64;
    __shared__ __align__(16) float4 sp[N];
    const int t = threadIdx.x, lane = t & 63, w = t >> 6;
    const int cen0 = blockIdx.x * WPB;
    const int b = cen0 / S;                     // WPB divides S -> same batch
    if (CHW) {
        const float* base = xyz + (size_t)b * 3 * N;
        for (int i = t; i < N; i += NT)
            sp[i] = make_float4(base[i], base[N + i], base[2 * N + i], 0.0f);
    } else {
        const float* base = xyz + (size_t)b * N * 3;
        for (int i = t; i < N; i += NT)
            sp[i] = make_float4(base[i*3], base[i*3+1], base[i*3+2], 0.0f);
    }
    __syncthreads();
    const int wid = cen0 + w;
    const float cx = cen[(size_t)wid*3+0], cy = cen[(size_t)wid*3+1], cz = cen[(size_t)wid*3+2];
    int* out = gidx + (size_t)wid * NS;
    int cnt = 0, first = -1;
    for (int b0 = 0; b0 < N; b0 += 64) {
        const float4 p = sp[b0 + lane];
        const float dx = p.x - cx, dy = p.y - cy, dz = p.z - cz;
        const float d = __fadd_rn(__fadd_rn(__fmul_rn(dx, dx), __fmul_rn(dy, dy)), __fmul_rn(dz, dz));
        const bool in = (d <= r2);
        const unsigned long long m = __ballot(in);
        if (first < 0 && m != 0ull) first = b0 + __ffsll((unsigned long long)m) - 1;
        const int pos = cnt + (int)__popcll(m & ((1ull << lane) - 1ull));
        if (in && pos < NS) out[pos] = b0 + lane;
        cnt += (int)__popcll(m);
        if (cnt >= NS) break;
    }
    if (cnt < NS)
        for (int k = cnt + lane; k < NS; k += 64) out[k] = first;
}

// ==================== weight pre-transpose (fused, one launch) =============
__device__ __forceinline__ void wt4_one(const float* __restrict__ w, float4* __restrict__ out,
                                        int O, int K, int reorder, int i) {
    const int o = i % O, cc = i / O;
    float v[4];
    #pragma unroll
    for (int u = 0; u < 4; ++u) {
        const int cp = cc * 4 + u;
        int c;
        if (reorder) c = (cp < K - 3) ? cp + 3 : (cp < K ? cp - (K - 3) : -1);
        else         c = (cp < K) ? cp : -1;
        v[u] = (c >= 0) ? w[(size_t)o * K + c] : 0.0f;
    }
    out[(size_t)cc * O + o] = make_float4(v[0], v[1], v[2], v[3]);
}

__global__ __launch_bounds__(256)
void wt4all_kernel(const float* w10, float4* o10, const float* w11, float4* o11,
                   const float* w12, float4* o12, const float* w20, float4* o20,
                   const float* w21, float4* o21, const float* w22, float4* o22) {
    int i = blockIdx.x * 256 + threadIdx.x;
    if (i < 64)        { wt4_one(w10, o10,  64,   3, 0, i); return; }       i -= 64;
    if (i < 1024)      { wt4_one(w11, o11,  64,  64, 0, i); return; }       i -= 1024;
    if (i < 2048)      { wt4_one(w12, o12, 128,  64, 0, i); return; }       i -= 2048;
    if (i < 4224)      { wt4_one(w20, o20, 128, 131, 1, i); return; }       i -= 4224;
    if (i < 4096)      { wt4_one(w21, o21, 128, 128, 0, i); return; }       i -= 4096;
    if (i < 8192)      { wt4_one(w22, o22, 256, 128, 0, i); return; }
}

// ===================== dense layer (LDS-staged weights) ====================
// 64 rows (LDS acts), O outputs. Weight chunks of 512 float4 (8KB) staged in
// wlds, shared by all waves; next chunk prefetched into 2 regs during compute.
// DOMAX=false: write relu to out (stride SOUT). DOMAX=true: per-thread max
// into red[rg*O + o] (acc persists across all chunks; NB row-blocks merged).
template<int O, int SIN, int SOUT, bool DOMAX>
__device__ __forceinline__ void dense_lds(
    const float4* __restrict__ W4g, const float* __restrict__ bias,
    const float* __restrict__ in, float* __restrict__ out,
    float4* __restrict__ wlds, int KC, int t) {
    constexpr int Q    = O / 4;          // lanes per o-group (o = q + Q*j)
    constexpr int RGRP = 256 / Q;        // row groups
    constexpr int RPT  = 64 / RGRP;      // rows per thread
    constexpr int NB   = (RPT + 7) / 8;
    constexpr int RB   = RPT < 8 ? RPT : 8;
    constexpr int CCT  = 512 / O;        // cc per 8KB chunk
    const int q  = t & (Q - 1);
    const int rg = t / Q;
    const int n0 = rg * RPT;

    float acc[NB][RB][4];
    #pragma unroll
    for (int nb = 0; nb < NB; ++nb)
        #pragma unroll
        for (int k = 0; k < RB; ++k)
            #pragma unroll
            for (int j = 0; j < 4; ++j) acc[nb][k][j] = bias[q + Q * j];

    // prefetch chunk 0
    float4 pf[2];
    {
        const int n0e = ((KC < CCT ? KC : CCT)) * O;
        #pragma unroll
        for (int r = 0; r < 2; ++r) {
            const int i = t + 256 * r;
            if (i < n0e) pf[r] = W4g[i];
        }
    }
    for (int chunk = 0; chunk < KC; chunk += CCT) {
        const int ncc = (KC - chunk) < CCT ? (KC - chunk) : CCT;
        __syncthreads();                           // wlds free (prev consumers done)
        #pragma unroll
        for (int r = 0; r < 2; ++r) {
            const int i = t + 256 * r;
            if (i < ncc * O) wlds[i] = pf[r];
        }
        __syncthreads();
        // prefetch next chunk during compute
        const int nchunk = chunk + CCT;
        if (nchunk < KC) {
            const int nncc = (KC - nchunk) < CCT ? (KC - nchunk) : CCT;
            #pragma unroll
            for (int r = 0; r < 2; ++r) {
                const int i = t + 256 * r;
                if (i < nncc * O) pf[r] = W4g[(size_t)nchunk * O + i];
            }
        }
        if (ncc == CCT) {
            #pragma unroll
            for (int ccl = 0; ccl < CCT; ++ccl) {
                float4 w[4];
                #pragma unroll
                for (int j = 0; j < 4; ++j) w[j] = wlds[ccl * O + q + Q * j];
                const int c4 = (chunk + ccl) * 4;
                #pragma unroll
                for (int nb = 0; nb < NB; ++nb)
                    #pragma unroll
                    for (int k = 0; k < RB; ++k) {
                        const float4 xv = *(const float4*)&in[(n0 + nb * RB + k) * SIN + c4];
                        #pragma unroll
                        for (int j = 0; j < 4; ++j)
                            acc[nb][k][j] += w[j].x*xv.x + w[j].y*xv.y + w[j].z*xv.z + w[j].w*xv.w;
                    }
            }
        } else {
            for (int ccl = 0; ccl < ncc; ++ccl) {
                float4 w[4];
                #pragma unroll
                for (int j = 0; j < 4; ++j) w[j] = wlds[ccl * O + q + Q * j];
                const int c4 = (chunk + ccl) * 4;
                #pragma unroll
                for (int nb = 0; nb < NB; ++nb)
                    #pragma unroll
                    for (int k = 0; k < RB; ++k) {
                        const float4 xv = *(const float4*)&in[(n0 + nb * RB + k) * SIN + c4];
                        #pragma unroll
                        for (int j = 0; j < 4; ++j)
                            acc[nb][k][j] += w[j].x*xv.x + w[j].y*xv.y + w[j].z*xv.z + w[j].w*xv.w;
                    }
            }
        }
    }
    if (DOMAX) {
        float m[4];
        #pragma unroll
        for (int j = 0; j < 4; ++j) m[j] = 0.0f;
        #pragma unroll
        for (int nb = 0; nb < NB; ++nb)
            #pragma unroll
            for (int k = 0; k < RB; ++k)
                #pragma unroll
                for (int j = 0; j < 4; ++j) m[j] = fmaxf(m[j], fmaxf(acc[nb][k][j], 0.0f));
        #pragma unroll
        for (int j = 0; j < 4; ++j) out[rg * O + q + Q * j] = m[j];
    } else {
        #pragma unroll
        for (int nb = 0; nb < NB; ++nb)
            #pragma unroll
            for (int k = 0; k < RB; ++k)
                #pragma unroll
                for (int j = 0; j < 4; ++j)
                    out[(n0 + nb * RB + k) * SOUT + q + Q * j] = fmaxf(acc[nb][k][j], 0.0f);
    }
}

// ============================ MLP stage 1 ==================================
// grid (256, 32): 2 s-tiles (64 rows) per block. LDS ~47KB -> 3 blocks/CU.
__global__ __launch_bounds__(256)
void mlp1_kernel(const float* __restrict__ xyz, const float* __restrict__ l1xyz,
                 const int* __restrict__ gidx,
                 const float4* __restrict__ W40, const float* __restrict__ b0,
                 const float4* __restrict__ W41, const float* __restrict__ b1,
                 const float4* __restrict__ W42, const float* __restrict__ b2,
                 float* __restrict__ l1p) {
    __shared__ __align__(16) float g[64 * 4];
    __shared__ __align__(16) float h1[64 * 68];
    __shared__ __align__(16) float h2[64 * 68];
    __shared__ __align__(16) float4 wlds[512];
    __shared__ float red[1024];
    const int t = threadIdx.x;
    const int b = blockIdx.y, s0 = blockIdx.x * 2;
    {
        const int n = t >> 2, c = t & 3;
        const int s = s0 + (n >> 5);
        const int gi = gidx[((size_t)b * 512 + s) * 32 + (n & 31)];
        float v = 0.0f;
        if (c < 3) v = xyz[(size_t)b * 3 * 4096 + c * 4096 + gi] - l1xyz[((size_t)b * 512 + s) * 3 + c];
        g[n * 4 + c] = v;
    }
    __syncthreads();
    dense_lds<64, 4, 68, false>(W40, b0, g, h1, wlds, 1, t);
    __syncthreads();
    dense_lds<64, 68, 68, false>(W41, b1, h1, h2, wlds, 16, t);
    __syncthreads();
    dense_lds<128, 68, 0, true>(W42, b2, h2, red, wlds, 16, t);
    __syncthreads();
    {
        const int half = t >> 7, o = t & 127;
        float v = red[(half * 4 + 0) * 128 + o];
        v = fmaxf(v, red[(half * 4 + 1) * 128 + o]);
        v = fmaxf(v, red[(half * 4 + 2) * 128 + o]);
        v = fmaxf(v, red[(half * 4 + 3) * 128 + o]);
        l1p[((size_t)b * 512 + s0 + half) * 128 + o] = v;
    }
}

// ============================ MLP stage 2 ==================================
// 4096 blocks, 1 centroid (64 rows). LDS ~77KB -> 2 blocks/CU.
__global__ __launch_bounds__(256)
void mlp2_kernel(const float* __restrict__ l1xyz, const float* __restrict__ l1p,
                 const float* __restrict__ l2xyz, const int* __restrict__ gidx,
                 const float4* __restrict__ W40, const float* __restrict__ b0,
                 const float4* __restrict__ W41, const float* __restrict__ b1,
                 const float4* __restrict__ W42, const float* __restrict__ b2,
                 float* __restrict__ X3) {
    __shared__ __align__(16) float xb[64 * 132];
    __shared__ __align__(16) float h1[64 * 128];
    __shared__ __align__(16) float4 wlds[512];
    __shared__ float red[1024];
    __shared__ int sg[64];
    const int t = threadIdx.x, bs = blockIdx.x, b = bs >> 7;
    if (t < 64) sg[t] = gidx[(size_t)bs * 64 + t];
    if (t < 3)  X3[(size_t)bs * 259 + t] = l2xyz[(size_t)bs * 3 + t];   // raw coords
    __syncthreads();
    {
        for (int i = t; i < 64 * 32; i += 256) {
            const int n = i >> 5, cc = i & 31;
            const float4 v = *(const float4*)&l1p[((size_t)b * 512 + sg[n]) * 128 + cc * 4];
            *(float4*)&xb[n * 132 + cc * 4] = v;
        }
        if (t < 192) {
            const int n = t / 3, c = t % 3;
            xb[n * 132 + 128 + c] =
                l1xyz[((size_t)b * 512 + sg[n]) * 3 + c] - l2xyz[(size_t)bs * 3 + c];
        }
        if (t < 64) xb[t * 132 + 131] = 0.0f;
    }
    __syncthreads();
    dense_lds<128, 132, 128, false>(W40, b0, xb, h1, wlds, 33, t);
    __syncthreads();
    dense_lds<128, 128, 128, false>(W41, b1, h1, xb, wlds, 32, t);
    __syncthreads();
    dense_lds<256, 128, 0, true>(W42, b2, xb, red, wlds, 32, t);
    __syncthreads();
    {
        float v = red[t];
        v = fmaxf(v, red[256 + t]);
        v = fmaxf(v, red[512 + t]);
        v = fmaxf(v, red[768 + t]);
        X3[(size_t)bs * 259 + 3 + t] = v;
    }
}

// ============================ Generic GEMM =================================
template<bool RELU>
__global__ __launch_bounds__(256)
void gemm_kernel(const float* __restrict__ A, const float* __restrict__ W,
                 const float* __restrict__ bias, float* __restrict__ C,
                 int M, int K, int O) {
    __shared__ __align__(16) float At[32*68];
    __shared__ __align__(16) float Wt[32*68];
    const int t = threadIdx.x;
    const int mtile = blockIdx.x * 64, otile = blockIdx.y * 64;
    const int tx = t & 15, ty = t >> 4;
    float acc[4][4];
    #pragma unroll
    for (int i = 0; i < 4; ++i)
        #pragma unroll
        for (int j = 0; j < 4; ++j) acc[i][j] = 0.0f;
    const int kk = t & 31, r0 = t >> 5;
    for (int k0 = 0; k0 < K; k0 += 32) {
        #pragma unroll
        for (int rr = 0; rr < 8; ++rr) {
            const int row = r0 + rr * 8;
            const int m = mtile + row, o = otile + row, k = k0 + kk;
            At[kk*68 + row] = (m < M && k < K) ? A[(size_t)m*K + k] : 0.0f;
            Wt[kk*68 + row] = (o < O && k < K) ? W[(size_t)o*K + k] : 0.0f;
        }
        __syncthreads();
        #pragma unroll
        for (int k2 = 0; k2 < 32; ++k2) {
            const float4 av = *(const float4*)&At[k2*68 + tx*4];
            const float4 wv = *(const float4*)&Wt[k2*68 + ty*4];
            const float a[4] = {av.x, av.y, av.z, av.w};
            const float w[4] = {wv.x, wv.y, wv.z, wv.w};
            #pragma unroll
            for (int i = 0; i < 4; ++i)
                #pragma unroll
                for (int j = 0; j < 4; ++j) acc[i][j] += a[i] * w[j];
        }
        __syncthreads();
    }
    #pragma unroll
    for (int i = 0; i < 4; ++i) {
        const int m = mtile + tx*4 + i;
        if (m >= M) continue;
        #pragma unroll
        for (int j = 0; j < 4; ++j) {
            const int o = otile + ty*4 + j;
            if (o >= O) continue;
            float v = acc[i][j] + bias[o];
            if (RELU) v = fmaxf(v, 0.0f);
            C[(size_t)m*O + o] = v;
        }
    }
}

// ============================ small utilities ==============================
__global__ __launch_bounds__(256)
void max128_kernel(const float* __restrict__ Y, float* __restrict__ feat) {
    const int idx = blockIdx.x * 256 + threadIdx.x;  // 32*1024
    const int b = idx >> 10, o = idx & 1023;
    const float* p = Y + (size_t)b * 128 * 1024 + o;
    float m = p[0];
    for (int n = 1; n < 128; ++n) m = fmaxf(m, p[(size_t)n * 1024]);
    feat[idx] = m;
}

// ============================ launch =======================================
extern "C" void kernel_launch(void* const* d_in, const int* in_sizes, int n_in,
                              void* d_out, int out_size, void* d_ws, size_t ws_size,
                              hipStream_t stream) {
    const float* xyz  = (const float*)d_in[0];
    const float* s1w0 = (const float*)d_in[1];  const float* s1b0 = (const float*)d_in[2];
    const float* s1w1 = (const float*)d_in[3];  const float* s1b1 = (const float*)d_in[4];
    const float* s1w2 = (const float*)d_in[5];  const float* s1b2 = (const float*)d_in[6];
    const float* s2w0 = (const float*)d_in[7];  const float* s2b0 = (const float*)d_in[8];
    const float* s2w1 = (const float*)d_in[9];  const float* s2b1 = (const float*)d_in[10];
    const float* s2w2 = (const float*)d_in[11]; const float* s2b2 = (const float*)d_in[12];
    const float* s3w0 = (const float*)d_in[13]; const float* s3b0 = (const float*)d_in[14];
    const float* s3w1 = (const float*)d_in[15]; const float* s3b1 = (const float*)d_in[16];
    const float* s3w2 = (const float*)d_in[17]; const float* s3b2 = (const float*)d_in[18];
    const float* f1w  = (const float*)d_in[19]; const float* f1b  = (const float*)d_in[20];
    const float* f2w  = (const float*)d_in[21]; const float* f2b  = (const float*)d_in[22];
    const float* f3w  = (const float*)d_in[23]; const float* f3b  = (const float*)d_in[24];

    char* ws = (char*)d_ws;
    float* l1_xyz = (float*)(ws + 0);              // 32*512*3
    int*   gidx1  = (int*)  (ws + 196608);         // 32*512*32
    float* l1p    = (float*)(ws + 2293760);        // 32*512*128
    float* l2_xyz = (float*)(ws + 10682368);       // 32*128*3
    int*   gidx2  = (int*)  (ws + 10731520);       // 32*128*64
    float* X3     = (float*)(ws + 11780096);       // 32*128*259
    float* Y1     = (float*)(ws + 16023552);       // 4096*256  (also hosts W4 buffers early)
    float* Y2     = (float*)(ws + 20217856);       // 4096*512
    float* Y3     = (float*)(ws + 28606464);       // 4096*1024
    float* feat   = (float*)(ws + 45383680);       // 32*1024
    float* fb1    = (float*)(ws + 45514752);       // 32*512
    float* fb2    = (float*)(ws + 45580288);       // 32*256

    // W4 buffers live in the Y1 region: consumed by mlp1/mlp2 BEFORE gemm1 writes Y1.
    float4* W4s10 = (float4*)(ws + 16023552);      // 1*64
    float4* W4s11 = (float4*)(ws + 16024576);      // 16*64
    float4* W4s12 = (float4*)(ws + 16040960);      // 16*128
    float4* W4s20 = (float4*)(ws + 16073728);      // 33*128
    float4* W4s21 = (float4*)(ws + 16141312);      // 32*128
    float4* W4s22 = (float4*)(ws + 16206848);      // 32*256

    wt4all_kernel<<<77, 256, 0, stream>>>(s1w0, W4s10, s1w1, W4s11, s1w2, W4s12,
                                          s2w0, W4s20, s2w1, W4s21, s2w2, W4s22);

    // Stage 1
    fps_kernel<4096, 512, 256, true><<<32, 256, 0, stream>>>(xyz, l1_xyz);
    bq_kernel<4096, 32, true, 1024><<<1024, 1024, 0, stream>>>(
        (float)(0.2 * 0.2), xyz, l1_xyz, gidx1, 512);
    {
        dim3 g(256, 32);
        mlp1_kernel<<<g, 256, 0, stream>>>(xyz, l1_xyz, gidx1,
            W4s10, s1b0, W4s11, s1b1, W4s12, s1b2, l1p);
    }

    // Stage 2
    fps_kernel<512, 128, 64, false><<<32, 64, 0, stream>>>(l1_xyz, l2_xyz);
    bq_kernel<512, 64, false, 1024><<<256, 1024, 0, stream>>>(
        (float)(0.4 * 0.4), l1_xyz, l2_xyz, gidx2, 128);
    mlp2_kernel<<<4096, 256, 0, stream>>>(l1_xyz, l1p, l2_xyz, gidx2,
        W4s20, s2b0, W4s21, s2b1, W4s22, s2b2, X3);

    // Stage 3 (group-all MLP as GEMMs over 4096 rows)
    {
        dim3 g1(64, 4);  gemm_kernel<true><<<g1, 256, 0, stream>>>(X3, s3w0, s3b0, Y1, 4096, 259, 256);
        dim3 g2(64, 8);  gemm_kernel<true><<<g2, 256, 0, stream>>>(Y1, s3w1, s3b1, Y2, 4096, 256, 512);
        dim3 g3(64, 16); gemm_kernel<true><<<g3, 256, 0, stream>>>(Y2, s3w2, s3b2, Y3, 4096, 512, 1024);
    }
    max128_kernel<<<128, 256, 0, stream>>>(Y3, feat);

    // FC head
    {
        dim3 g1(1, 8); gemm_kernel<true><<<g1, 256, 0, stream>>>(feat, f1w, f1b, fb1, 32, 1024, 512);
        dim3 g2(1, 4); gemm_kernel<true><<<g2, 256, 0, stream>>>(fb1, f2w, f2b, fb2, 32, 512, 256);
        dim3 g3(1, 1); gemm_kernel<false><<<g3, 256, 0, stream>>>(fb2, f3w, f3b, (float*)d_out, 32, 256, 6);
    }
    (void)in_sizes; (void)n_in; (void)out_size; (void)ws_size;
}

// Round 7
// 1329.601 us; speedup vs baseline: 1.8474x; 1.8474x over previous
//
#include <hip/hip_runtime.h>
#include <hip/hip_bf16.h>

// ---------------------------------------------------------------------------
// PointNet++ critic forward. B=32, N=4096.
// R7: mlp2 rewritten on MFMA bf16-split (3-pass hi/lo, fp32 acc): weights
// pre-split+tile-packed (lane-linear 1KB blocks, coalesced), acts fp32 in LDS
// converted per k-step, coords as exact fp32 epilogue fixup. mlp1 = R5 form.
// ---------------------------------------------------------------------------

typedef __attribute__((ext_vector_type(8))) short short8;
typedef __attribute__((ext_vector_type(4))) float f32x4;
union SV8 { short8 v; ushort u[8]; };

__device__ __forceinline__ ushort f2bf(float x) {
    unsigned u = __float_as_uint(x);
    unsigned r = (u + 0x7fffu + ((u >> 16) & 1u)) >> 16;   // RNE
    return (ushort)r;
}
__device__ __forceinline__ float bf2f(ushort h) {
    return __uint_as_float(((unsigned)h) << 16);
}

// ======================= DPP wave64 max-reduce (u64) =======================
template<int CTRL>
__device__ __forceinline__ unsigned long long dpp_mov_u64(unsigned long long x) {
    const int lo = (int)(unsigned)(x & 0xffffffffull);
    const int hi = (int)(unsigned)(x >> 32);
    const int nlo = __builtin_amdgcn_update_dpp(lo, lo, CTRL, 0xf, 0xf, false);
    const int nhi = __builtin_amdgcn_update_dpp(hi, hi, CTRL, 0xf, 0xf, false);
    return ((unsigned long long)(unsigned)nhi << 32) | (unsigned)nlo;
}

__device__ __forceinline__ unsigned long long wave_max_u64(unsigned long long x) {
    unsigned long long y;
    y = dpp_mov_u64<0x111>(x); if (y > x) x = y;   // row_shr:1
    y = dpp_mov_u64<0x112>(x); if (y > x) x = y;   // row_shr:2
    y = dpp_mov_u64<0x114>(x); if (y > x) x = y;   // row_shr:4
    y = dpp_mov_u64<0x118>(x); if (y > x) x = y;   // row_shr:8
    y = dpp_mov_u64<0x142>(x); if (y > x) x = y;   // row_bcast:15
    y = dpp_mov_u64<0x143>(x); if (y > x) x = y;   // row_bcast:31
    return x;
}

// ============================ FPS ==========================================
template<int N, int S, int NT, bool CHW>
__global__ __launch_bounds__(NT)
void fps_kernel(const float* __restrict__ xyz, float* __restrict__ new_xyz) {
    constexpr int P  = N / NT;
    constexpr int NW = NT / 64;
    __shared__ __align__(16) float4 sxyz[N];
    __shared__ __align__(16) unsigned long long rv[2][NW > 1 ? NW : 2];
    const int b = blockIdx.x, t = threadIdx.x;
    float px[P], py[P], pz[P], dist[P];
    if (CHW) {
        const float* base = xyz + (size_t)b * 3 * N;
        #pragma unroll
        for (int p = 0; p < P; ++p) {
            const int i = p * NT + t;
            px[p] = base[i]; py[p] = base[N + i]; pz[p] = base[2 * N + i];
            sxyz[i] = make_float4(px[p], py[p], pz[p], 0.0f);
        }
    } else {
        const float* base = xyz + (size_t)b * N * 3;
        #pragma unroll
        for (int p = 0; p < P; ++p) {
            const int i = p * NT + t;
            px[p] = base[i*3]; py[p] = base[i*3+1]; pz[p] = base[i*3+2];
            sxyz[i] = make_float4(px[p], py[p], pz[p], 0.0f);
        }
    }
    #pragma unroll
    for (int p = 0; p < P; ++p) dist[p] = 1e10f;
    __syncthreads();
    int far = 0;
    float* out = new_xyz + (size_t)b * S * 3;
    for (int j = 0; j < S; ++j) {
        const float4 cen = sxyz[far];            // broadcast b128
        if (t == 0) { out[j*3+0] = cen.x; out[j*3+1] = cen.y; out[j*3+2] = cen.z; }
        float bv = -1.0f; int bi = 0;
        #pragma unroll
        for (int p = 0; p < P; ++p) {
            const int i = p * NT + t;
            const float dx = px[p] - cen.x, dy = py[p] - cen.y, dz = pz[p] - cen.z;
            // match reference rounding exactly: no FMA contraction
            const float d = __fadd_rn(__fadd_rn(__fmul_rn(dx, dx), __fmul_rn(dy, dy)), __fmul_rn(dz, dz));
            const float nd = fminf(dist[p], d);
            dist[p] = nd;
            if (nd > bv) { bv = nd; bi = i; }    // strict > keeps smallest i
        }
        unsigned long long pk =
            ((unsigned long long)__float_as_uint(bv) << 32) | (unsigned)(N - 1 - bi);
        pk = wave_max_u64(pk);
        if constexpr (NW > 1) {
            const int sl = j & 1;
            if ((t & 63) == 63) rv[sl][t >> 6] = pk;
            __syncthreads();
            unsigned long long best = rv[sl][0];
            #pragma unroll
            for (int w = 1; w < NW; ++w) { const unsigned long long v = rv[sl][w]; if (v > best) best = v; }
            far = N - 1 - (int)(best & 0xffffffffull);
        } else {
            far = N - 1 - __builtin_amdgcn_readlane((int)(pk & 0xffffffffull), 63);
        }
    }
}

// ============================ Ball query ===================================
template<int N, int NS, bool CHW, int NT>
__global__ __launch_bounds__(NT)
void bq_kernel(float r2, const float* __restrict__ xyz, const float* __restrict__ cen,
               int* __restrict__ gidx, int S) {
    constexpr int WPB = NT / 64;
    __shared__ __align__(16) float4 sp[N];
    const int t = threadIdx.x, lane = t & 63, w = t >> 6;
    const int cen0 = blockIdx.x * WPB;
    const int b = cen0 / S;                     // WPB divides S -> same batch
    if (CHW) {
        const float* base = xyz + (size_t)b * 3 * N;
        for (int i = t; i < N; i += NT)
            sp[i] = make_float4(base[i], base[N + i], base[2 * N + i], 0.0f);
    } else {
        const float* base = xyz + (size_t)b * N * 3;
        for (int i = t; i < N; i += NT)
            sp[i] = make_float4(base[i*3], base[i*3+1], base[i*3+2], 0.0f);
    }
    __syncthreads();
    const int wid = cen0 + w;
    const float cx = cen[(size_t)wid*3+0], cy = cen[(size_t)wid*3+1], cz = cen[(size_t)wid*3+2];
    int* out = gidx + (size_t)wid * NS;
    int cnt = 0, first = -1;
    for (int b0 = 0; b0 < N; b0 += 64) {
        const float4 p = sp[b0 + lane];
        const float dx = p.x - cx, dy = p.y - cy, dz = p.z - cz;
        const float d = __fadd_rn(__fadd_rn(__fmul_rn(dx, dx), __fmul_rn(dy, dy)), __fmul_rn(dz, dz));
        const bool in = (d <= r2);
        const unsigned long long m = __ballot(in);
        if (first < 0 && m != 0ull) first = b0 + __ffsll((unsigned long long)m) - 1;
        const int pos = cnt + (int)__popcll(m & ((1ull << lane) - 1ull));
        if (in && pos < NS) out[pos] = b0 + lane;
        cnt += (int)__popcll(m);
        if (cnt >= NS) break;
    }
    if (cnt < NS)
        for (int k = cnt + lane; k < NS; k += 64) out[k] = first;
}

// ==================== mlp1 weight pre-transpose ============================
__device__ __forceinline__ void wt4_one(const float* __restrict__ w, float4* __restrict__ out,
                                        int O, int K, int i) {
    const int o = i % O, cc = i / O;
    float v[4];
    #pragma unroll
    for (int u = 0; u < 4; ++u) {
        const int c = cc * 4 + u;
        v[u] = (c < K) ? w[(size_t)o * K + c] : 0.0f;
    }
    out[(size_t)cc * O + o] = make_float4(v[0], v[1], v[2], v[3]);
}

__global__ __launch_bounds__(256)
void wt4all_kernel(const float* w10, float4* o10, const float* w11, float4* o11,
                   const float* w12, float4* o12) {
    int i = blockIdx.x * 256 + threadIdx.x;
    if (i < 64)   { wt4_one(w10, o10,  64,  3, i); return; }   i -= 64;
    if (i < 1024) { wt4_one(w11, o11,  64, 64, i); return; }   i -= 1024;
    if (i < 2048) { wt4_one(w12, o12, 128, 64, i); return; }
}

// ==================== mlp2 weight split + tile pack ========================
// Layout: [kstep][otile][lane][8] bf16, lane = q*16+m -> element W[ot*16+m][ks*32+q*8+j]
__global__ __launch_bounds__(256)
void wpack2_kernel(const float* __restrict__ w0, const float* __restrict__ b0,
                   const float* __restrict__ w1, const float* __restrict__ w2,
                   ushort* __restrict__ W0h, ushort* __restrict__ W0l,
                   ushort* __restrict__ W1h, ushort* __restrict__ W1l,
                   ushort* __restrict__ W2h, ushort* __restrict__ W2l,
                   float4* __restrict__ Wc0) {
    int i = blockIdx.x * 256 + threadIdx.x;
    if (i < 65536) {
        const float* src; ushort *dh, *dl; int idx, NOTM, K, cofs;
        if (i < 16384)      { src = w0; dh = W0h; dl = W0l; idx = i;        NOTM = 7;  K = 131; cofs = 3; }
        else if (i < 32768) { src = w1; dh = W1h; dl = W1l; idx = i-16384;  NOTM = 7;  K = 128; cofs = 0; }
        else                { src = w2; dh = W2h; dl = W2l; idx = i-32768;  NOTM = 15; K = 128; cofs = 0; }
        const int j = idx & 7, lane = (idx >> 3) & 63;
        const int ot = (idx >> 9) & NOTM, ks = idx >> (NOTM == 7 ? 12 : 13);
        const int m = lane & 15, q = lane >> 4;
        const int o = ot * 16 + m, c = cofs + ks * 32 + q * 8 + j;
        const float v = src[(size_t)o * K + c];
        const ushort h = f2bf(v);
        dh[idx] = h;
        dl[idx] = f2bf(v - bf2f(h));
    } else if (i < 65664) {
        const int o = i - 65536;
        Wc0[o] = make_float4(w0[(size_t)o*131+0], w0[(size_t)o*131+1], w0[(size_t)o*131+2], b0[o]);
    }
}

// ===================== dense layer (R5 ping-pong, for mlp1) ================
template<int O, int SIN, int SOUT>
__device__ __forceinline__ void dense_relu(
    const float4* __restrict__ W4, const float* __restrict__ bias,
    const float* __restrict__ in, float* __restrict__ out, int KC, int t) {
    constexpr int Q   = O / 4;
    constexpr int RPT = Q / 4;
    constexpr int NB  = (RPT + 7) / 8;
    constexpr int RB  = RPT < 8 ? RPT : 8;
    const int q = t & (Q - 1);
    const int rg = t / Q;
    const int n0 = rg * RPT;
    float bb[4];
    #pragma unroll
    for (int j = 0; j < 4; ++j) bb[j] = bias[q + Q * j];
    #pragma unroll
    for (int nb = 0; nb < NB; ++nb) {
        float acc[RB][4];
        #pragma unroll
        for (int k = 0; k < RB; ++k)
            #pragma unroll
            for (int j = 0; j < 4; ++j) acc[k][j] = bb[j];
        const float* inb = in + (n0 + nb * 8) * SIN;
        float4 wa[4], wb[4];
        #pragma unroll
        for (int j = 0; j < 4; ++j) wa[j] = W4[q + Q * j];
        int cc = 0;
        for (; cc + 2 <= KC; cc += 2) {
            #pragma unroll
            for (int j = 0; j < 4; ++j) wb[j] = W4[(size_t)(cc + 1) * O + q + Q * j];
            #pragma unroll
            for (int k = 0; k < RB; ++k) {
                const float4 xv = *(const float4*)&inb[k * SIN + cc * 4];
                #pragma unroll
                for (int j = 0; j < 4; ++j)
                    acc[k][j] += wa[j].x * xv.x + wa[j].y * xv.y + wa[j].z * xv.z + wa[j].w * xv.w;
            }
            const int cn = (cc + 2 < KC) ? cc + 2 : cc;
            #pragma unroll
            for (int j = 0; j < 4; ++j) wa[j] = W4[(size_t)cn * O + q + Q * j];
            #pragma unroll
            for (int k = 0; k < RB; ++k) {
                const float4 xv = *(const float4*)&inb[k * SIN + cc * 4 + 4];
                #pragma unroll
                for (int j = 0; j < 4; ++j)
                    acc[k][j] += wb[j].x * xv.x + wb[j].y * xv.y + wb[j].z * xv.z + wb[j].w * xv.w;
            }
        }
        if (cc < KC) {
            #pragma unroll
            for (int k = 0; k < RB; ++k) {
                const float4 xv = *(const float4*)&inb[k * SIN + cc * 4];
                #pragma unroll
                for (int j = 0; j < 4; ++j)
                    acc[k][j] += wa[j].x * xv.x + wa[j].y * xv.y + wa[j].z * xv.z + wa[j].w * xv.w;
            }
        }
        #pragma unroll
        for (int k = 0; k < RB; ++k)
            #pragma unroll
            for (int j = 0; j < 4; ++j)
                out[(n0 + nb * 8 + k) * SOUT + q + Q * j] = fmaxf(acc[k][j], 0.0f);
    }
}

template<int O, int SIN>
__device__ __forceinline__ void dense_relu_max(
    const float4* __restrict__ W4, const float* __restrict__ bias,
    const float* __restrict__ in, float* __restrict__ red, int KC, int t) {
    constexpr int Q   = O / 4;
    constexpr int RPT = Q / 4;
    constexpr int NB  = (RPT + 7) / 8;
    constexpr int RB  = RPT < 8 ? RPT : 8;
    const int q = t & (Q - 1);
    const int rg = t / Q;
    const int n0 = rg * RPT;
    float bb[4], m[4];
    #pragma unroll
    for (int j = 0; j < 4; ++j) { bb[j] = bias[q + Q * j]; m[j] = 0.0f; }
    #pragma unroll
    for (int nb = 0; nb < NB; ++nb) {
        float acc[RB][4];
        #pragma unroll
        for (int k = 0; k < RB; ++k)
            #pragma unroll
            for (int j = 0; j < 4; ++j) acc[k][j] = bb[j];
        const float* inb = in + (n0 + nb * 8) * SIN;
        float4 wa[4], wb[4];
        #pragma unroll
        for (int j = 0; j < 4; ++j) wa[j] = W4[q + Q * j];
        int cc = 0;
        for (; cc + 2 <= KC; cc += 2) {
            #pragma unroll
            for (int j = 0; j < 4; ++j) wb[j] = W4[(size_t)(cc + 1) * O + q + Q * j];
            #pragma unroll
            for (int k = 0; k < RB; ++k) {
                const float4 xv = *(const float4*)&inb[k * SIN + cc * 4];
                #pragma unroll
                for (int j = 0; j < 4; ++j)
                    acc[k][j] += wa[j].x * xv.x + wa[j].y * xv.y + wa[j].z * xv.z + wa[j].w * xv.w;
            }
            const int cn = (cc + 2 < KC) ? cc + 2 : cc;
            #pragma unroll
            for (int j = 0; j < 4; ++j) wa[j] = W4[(size_t)cn * O + q + Q * j];
            #pragma unroll
            for (int k = 0; k < RB; ++k) {
                const float4 xv = *(const float4*)&inb[k * SIN + cc * 4 + 4];
                #pragma unroll
                for (int j = 0; j < 4; ++j)
                    acc[k][j] += wb[j].x * xv.x + wb[j].y * xv.y + wb[j].z * xv.z + wb[j].w * xv.w;
            }
        }
        if (cc < KC) {
            #pragma unroll
            for (int k = 0; k < RB; ++k) {
                const float4 xv = *(const float4*)&inb[k * SIN + cc * 4];
                #pragma unroll
                for (int j = 0; j < 4; ++j)
                    acc[k][j] += wa[j].x * xv.x + wa[j].y * xv.y + wa[j].z * xv.z + wa[j].w * xv.w;
            }
        }
        #pragma unroll
        for (int k = 0; k < RB; ++k)
            #pragma unroll
            for (int j = 0; j < 4; ++j) m[j] = fmaxf(m[j], fmaxf(acc[k][j], 0.0f));
    }
    #pragma unroll
    for (int j = 0; j < 4; ++j) red[rg * O + q + Q * j] = m[j];
}

// ============================ MLP stage 1 (R5) =============================
__global__ __launch_bounds__(256)
void mlp1_kernel(const float* __restrict__ xyz, const float* __restrict__ l1xyz,
                 const int* __restrict__ gidx,
                 const float4* __restrict__ W40, const float* __restrict__ b0,
                 const float4* __restrict__ W41, const float* __restrict__ b1,
                 const float4* __restrict__ W42, const float* __restrict__ b2,
                 float* __restrict__ l1p) {
    __shared__ __align__(16) float g[64 * 4];
    __shared__ __align__(16) float h1[64 * 68];
    __shared__ __align__(16) float h2[64 * 68];
    __shared__ float red[1024];
    const int t = threadIdx.x;
    const int b = blockIdx.y, s0 = blockIdx.x * 2;
    {
        const int n = t >> 2, c = t & 3;
        const int s = s0 + (n >> 5);
        const int gi = gidx[((size_t)b * 512 + s) * 32 + (n & 31)];
        float v = 0.0f;
        if (c < 3) v = xyz[(size_t)b * 3 * 4096 + c * 4096 + gi] - l1xyz[((size_t)b * 512 + s) * 3 + c];
        g[n * 4 + c] = v;
    }
    __syncthreads();
    dense_relu<64, 4, 68>(W40, b0, g, h1, 1, t);
    __syncthreads();
    dense_relu<64, 68, 68>(W41, b1, h1, h2, 16, t);
    __syncthreads();
    dense_relu_max<128, 68>(W42, b2, h2, red, 16, t);
    __syncthreads();
    {
        const int half = t >> 7, o = t & 127;
        float v = red[(half * 4 + 0) * 128 + o];
        v = fmaxf(v, red[(half * 4 + 1) * 128 + o]);
        v = fmaxf(v, red[(half * 4 + 2) * 128 + o]);
        v = fmaxf(v, red[(half * 4 + 3) * 128 + o]);
        l1p[((size_t)b * 512 + s0 + half) * 128 + o] = v;
    }
}

// ============================ MLP stage 2 (MFMA) ===========================
// 4096 blocks x 256 thr (4 waves). Wave w owns rows w*16..w*16+15.
// Acts fp32 in LDS (stride 132); per k-step converted to bf16 hi/lo A-frags.
// Weights: tile-packed bf16 hi/lo from global (coalesced, shared by waves).
// 3-pass MFMA: Ah*Bh + Al*Bh + Ah*Bl into fp32 acc. Coords: exact epilogue.
__global__ __launch_bounds__(256)
void mlp2_kernel(const float* __restrict__ l1xyz, const float* __restrict__ l1p,
                 const float* __restrict__ l2xyz, const int* __restrict__ gidx,
                 const ushort* __restrict__ W0h, const ushort* __restrict__ W0l,
                 const float4* __restrict__ Wc0,
                 const ushort* __restrict__ W1h, const ushort* __restrict__ W1l,
                 const float* __restrict__ b1,
                 const ushort* __restrict__ W2h, const ushort* __restrict__ W2l,
                 const float* __restrict__ b2,
                 float* __restrict__ X3) {
    __shared__ __align__(16) float Abuf[64 * 132];   // x / h2
    __shared__ __align__(16) float Bbuf[64 * 132];   // h1 / max-partials
    __shared__ int sg[64];
    const int t = threadIdx.x, bs = blockIdx.x, b = bs >> 7;
    if (t < 64) sg[t] = gidx[(size_t)bs * 64 + t];
    if (t < 3)  X3[(size_t)bs * 259 + t] = l2xyz[(size_t)bs * 3 + t];   // raw coords
    __syncthreads();
    for (int i = t; i < 64 * 32; i += 256) {
        const int n = i >> 5, cc = i & 31;
        *(float4*)&Abuf[n * 132 + cc * 4] =
            *(const float4*)&l1p[((size_t)b * 512 + sg[n]) * 128 + cc * 4];
    }
    if (t < 192) {
        const int n = t / 3, c = t % 3;
        Abuf[n * 132 + 128 + c] =
            l1xyz[((size_t)b * 512 + sg[n]) * 3 + c] - l2xyz[(size_t)bs * 3 + c];
    }
    __syncthreads();
    const int lane = t & 63, wv = t >> 6;
    const int m = lane & 15, q = lane >> 4;
    const int rowA = wv * 16 + m;                    // this lane's A-frag row

    // ---------- layer 0: feats (K=128) MFMA + coords/bias epilogue ----------
    f32x4 acc0[8];
    #pragma unroll
    for (int ot = 0; ot < 8; ++ot)
        #pragma unroll
        for (int r = 0; r < 4; ++r) acc0[ot][r] = 0.0f;
    #pragma unroll
    for (int ks = 0; ks < 4; ++ks) {
        float xv[8];
        *(float4*)&xv[0] = *(const float4*)&Abuf[rowA * 132 + ks * 32 + q * 8];
        *(float4*)&xv[4] = *(const float4*)&Abuf[rowA * 132 + ks * 32 + q * 8 + 4];
        SV8 ah, al;
        #pragma unroll
        for (int j = 0; j < 8; ++j) {
            ah.u[j] = f2bf(xv[j]);
            al.u[j] = f2bf(xv[j] - bf2f(ah.u[j]));
        }
        #pragma unroll
        for (int ot = 0; ot < 8; ++ot) {
            SV8 bh, bl;
            bh.v = *(const short8*)(W0h + (size_t)((ks * 8 + ot) * 64 + lane) * 8);
            bl.v = *(const short8*)(W0l + (size_t)((ks * 8 + ot) * 64 + lane) * 8);
            acc0[ot] = __builtin_amdgcn_mfma_f32_16x16x32_bf16(ah.v, bh.v, acc0[ot], 0, 0, 0);
            acc0[ot] = __builtin_amdgcn_mfma_f32_16x16x32_bf16(al.v, bh.v, acc0[ot], 0, 0, 0);
            acc0[ot] = __builtin_amdgcn_mfma_f32_16x16x32_bf16(ah.v, bl.v, acc0[ot], 0, 0, 0);
        }
    }
    float crd[4][3];
    #pragma unroll
    for (int r = 0; r < 4; ++r) {
        const int n = wv * 16 + q * 4 + r;
        crd[r][0] = Abuf[n * 132 + 128];
        crd[r][1] = Abuf[n * 132 + 129];
        crd[r][2] = Abuf[n * 132 + 130];
    }
    #pragma unroll
    for (int ot = 0; ot < 8; ++ot) {
        const float4 wc = Wc0[ot * 16 + m];
        #pragma unroll
        for (int r = 0; r < 4; ++r) {
            const float v = acc0[ot][r] + wc.w + wc.x * crd[r][0] + wc.y * crd[r][1] + wc.z * crd[r][2];
            Bbuf[(wv * 16 + q * 4 + r) * 132 + ot * 16 + m] = fmaxf(v, 0.0f);
        }
    }
    __syncthreads();

    // ---------- layer 1: 128 -> 128 ----------
    f32x4 acc1[8];
    #pragma unroll
    for (int ot = 0; ot < 8; ++ot)
        #pragma unroll
        for (int r = 0; r < 4; ++r) acc1[ot][r] = 0.0f;
    #pragma unroll
    for (int ks = 0; ks < 4; ++ks) {
        float xv[8];
        *(float4*)&xv[0] = *(const float4*)&Bbuf[rowA * 132 + ks * 32 + q * 8];
        *(float4*)&xv[4] = *(const float4*)&Bbuf[rowA * 132 + ks * 32 + q * 8 + 4];
        SV8 ah, al;
        #pragma unroll
        for (int j = 0; j < 8; ++j) {
            ah.u[j] = f2bf(xv[j]);
            al.u[j] = f2bf(xv[j] - bf2f(ah.u[j]));
        }
        #pragma unroll
        for (int ot = 0; ot < 8; ++ot) {
            SV8 bh, bl;
            bh.v = *(const short8*)(W1h + (size_t)((ks * 8 + ot) * 64 + lane) * 8);
            bl.v = *(const short8*)(W1l + (size_t)((ks * 8 + ot) * 64 + lane) * 8);
            acc1[ot] = __builtin_amdgcn_mfma_f32_16x16x32_bf16(ah.v, bh.v, acc1[ot], 0, 0, 0);
            acc1[ot] = __builtin_amdgcn_mfma_f32_16x16x32_bf16(al.v, bh.v, acc1[ot], 0, 0, 0);
            acc1[ot] = __builtin_amdgcn_mfma_f32_16x16x32_bf16(ah.v, bl.v, acc1[ot], 0, 0, 0);
        }
    }
    __syncthreads();   // Bbuf reads done before Abuf rewrite? (Abuf is target; reads were Bbuf) -- keep order safe
    #pragma unroll
    for (int ot = 0; ot < 8; ++ot) {
        const float bb = b1[ot * 16 + m];
        #pragma unroll
        for (int r = 0; r < 4; ++r)
            Abuf[(wv * 16 + q * 4 + r) * 132 + ot * 16 + m] = fmaxf(acc1[ot][r] + bb, 0.0f);
    }
    __syncthreads();

    // ---------- layer 2: 128 -> 256, relu+max over rows ----------
    f32x4 acc2[16];
    #pragma unroll
    for (int ot = 0; ot < 16; ++ot)
        #pragma unroll
        for (int r = 0; r < 4; ++r) acc2[ot][r] = 0.0f;
    #pragma unroll
    for (int ks = 0; ks < 4; ++ks) {
        float xv[8];
        *(float4*)&xv[0] = *(const float4*)&Abuf[rowA * 132 + ks * 32 + q * 8];
        *(float4*)&xv[4] = *(const float4*)&Abuf[rowA * 132 + ks * 32 + q * 8 + 4];
        SV8 ah, al;
        #pragma unroll
        for (int j = 0; j < 8; ++j) {
            ah.u[j] = f2bf(xv[j]);
            al.u[j] = f2bf(xv[j] - bf2f(ah.u[j]));
        }
        #pragma unroll
        for (int ot = 0; ot < 16; ++ot) {
            SV8 bh, bl;
            bh.v = *(const short8*)(W2h + (size_t)((ks * 16 + ot) * 64 + lane) * 8);
            bl.v = *(const short8*)(W2l + (size_t)((ks * 16 + ot) * 64 + lane) * 8);
            acc2[ot] = __builtin_amdgcn_mfma_f32_16x16x32_bf16(ah.v, bh.v, acc2[ot], 0, 0, 0);
            acc2[ot] = __builtin_amdgcn_mfma_f32_16x16x32_bf16(al.v, bh.v, acc2[ot], 0, 0, 0);
            acc2[ot] = __builtin_amdgcn_mfma_f32_16x16x32_bf16(ah.v, bl.v, acc2[ot], 0, 0, 0);
        }
    }
    __syncthreads();   // all Abuf reads done; Bbuf free to reuse for partials
    #pragma unroll
    for (int ot = 0; ot < 16; ++ot) {
        const float bb = b2[ot * 16 + m];
        float mx = 0.0f;
        #pragma unroll
        for (int r = 0; r < 4; ++r) mx = fmaxf(mx, acc2[ot][r] + bb);   // relu via mx>=0
        Bbuf[(wv * 4 + q) * 256 + ot * 16 + m] = mx;
    }
    __syncthreads();
    {   // final max over 16 partial rows; o = t
        float v = Bbuf[t];
        #pragma unroll
        for (int rr = 1; rr < 16; ++rr) v = fmaxf(v, Bbuf[rr * 256 + t]);
        X3[(size_t)bs * 259 + 3 + t] = v;
    }
}

// ============================ Generic GEMM =================================
template<bool RELU>
__global__ __launch_bounds__(256)
void gemm_kernel(const float* __restrict__ A, const float* __restrict__ W,
                 const float* __restrict__ bias, float* __restrict__ C,
                 int M, int K, int O) {
    __shared__ __align__(16) float At[32*68];
    __shared__ __align__(16) float Wt[32*68];
    const int t = threadIdx.x;
    const int mtile = blockIdx.x * 64, otile = blockIdx.y * 64;
    const int tx = t & 15, ty = t >> 4;
    float acc[4][4];
    #pragma unroll
    for (int i = 0; i < 4; ++i)
        #pragma unroll
        for (int j = 0; j < 4; ++j) acc[i][j] = 0.0f;
    const int kk = t & 31, r0 = t >> 5;
    for (int k0 = 0; k0 < K; k0 += 32) {
        #pragma unroll
        for (int rr = 0; rr < 8; ++rr) {
            const int row = r0 + rr * 8;
            const int m = mtile + row, o = otile + row, k = k0 + kk;
            At[kk*68 + row] = (m < M && k < K) ? A[(size_t)m*K + k] : 0.0f;
            Wt[kk*68 + row] = (o < O && k < K) ? W[(size_t)o*K + k] : 0.0f;
        }
        __syncthreads();
        #pragma unroll
        for (int k2 = 0; k2 < 32; ++k2) {
            const float4 av = *(const float4*)&At[k2*68 + tx*4];
            const float4 wv = *(const float4*)&Wt[k2*68 + ty*4];
            const float a[4] = {av.x, av.y, av.z, av.w};
            const float w[4] = {wv.x, wv.y, wv.z, wv.w};
            #pragma unroll
            for (int i = 0; i < 4; ++i)
                #pragma unroll
                for (int j = 0; j < 4; ++j) acc[i][j] += a[i] * w[j];
        }
        __syncthreads();
    }
    #pragma unroll
    for (int i = 0; i < 4; ++i) {
        const int m = mtile + tx*4 + i;
        if (m >= M) continue;
        #pragma unroll
        for (int j = 0; j < 4; ++j) {
            const int o = otile + ty*4 + j;
            if (o >= O) continue;
            float v = acc[i][j] + bias[o];
            if (RELU) v = fmaxf(v, 0.0f);
            C[(size_t)m*O + o] = v;
        }
    }
}

// ============================ small utilities ==============================
__global__ __launch_bounds__(256)
void max128_kernel(const float* __restrict__ Y, float* __restrict__ feat) {
    const int idx = blockIdx.x * 256 + threadIdx.x;  // 32*1024
    const int b = idx >> 10, o = idx & 1023;
    const float* p = Y + (size_t)b * 128 * 1024 + o;
    float m = p[0];
    for (int n = 1; n < 128; ++n) m = fmaxf(m, p[(size_t)n * 1024]);
    feat[idx] = m;
}

// ============================ launch =======================================
extern "C" void kernel_launch(void* const* d_in, const int* in_sizes, int n_in,
                              void* d_out, int out_size, void* d_ws, size_t ws_size,
                              hipStream_t stream) {
    const float* xyz  = (const float*)d_in[0];
    const float* s1w0 = (const float*)d_in[1];  const float* s1b0 = (const float*)d_in[2];
    const float* s1w1 = (const float*)d_in[3];  const float* s1b1 = (const float*)d_in[4];
    const float* s1w2 = (const float*)d_in[5];  const float* s1b2 = (const float*)d_in[6];
    const float* s2w0 = (const float*)d_in[7];  const float* s2b0 = (const float*)d_in[8];
    const float* s2w1 = (const float*)d_in[9];  const float* s2b1 = (const float*)d_in[10];
    const float* s2w2 = (const float*)d_in[11]; const float* s2b2 = (const float*)d_in[12];
    const float* s3w0 = (const float*)d_in[13]; const float* s3b0 = (const float*)d_in[14];
    const float* s3w1 = (const float*)d_in[15]; const float* s3b1 = (const float*)d_in[16];
    const float* s3w2 = (const float*)d_in[17]; const float* s3b2 = (const float*)d_in[18];
    const float* f1w  = (const float*)d_in[19]; const float* f1b  = (const float*)d_in[20];
    const float* f2w  = (const float*)d_in[21]; const float* f2b  = (const float*)d_in[22];
    const float* f3w  = (const float*)d_in[23]; const float* f3b  = (const float*)d_in[24];

    char* ws = (char*)d_ws;
    float* l1_xyz = (float*)(ws + 0);              // 32*512*3
    int*   gidx1  = (int*)  (ws + 196608);         // 32*512*32
    float* l1p    = (float*)(ws + 2293760);        // 32*512*128
    float* l2_xyz = (float*)(ws + 10682368);       // 32*128*3
    int*   gidx2  = (int*)  (ws + 10731520);       // 32*128*64
    float* X3     = (float*)(ws + 11780096);       // 32*128*259
    float* Y1     = (float*)(ws + 16023552);       // 4096*256  (hosts W buffers early)
    float* Y2     = (float*)(ws + 20217856);       // 4096*512
    float* Y3     = (float*)(ws + 28606464);       // 4096*1024
    float* feat   = (float*)(ws + 45383680);       // 32*1024
    float* fb1    = (float*)(ws + 45514752);       // 32*512
    float* fb2    = (float*)(ws + 45580288);       // 32*256

    // Weight buffers live in the Y1 region (consumed before gemm1 writes Y1).
    const size_t base = 16023552;
    float4* W4s10 = (float4*)(ws + base + 0);       // 1*64   *16B
    float4* W4s11 = (float4*)(ws + base + 1024);    // 16*64
    float4* W4s12 = (float4*)(ws + base + 17408);   // 16*128
    ushort* W0h   = (ushort*)(ws + base + 50176);   // 16384 *2B
    ushort* W0l   = (ushort*)(ws + base + 82944);
    ushort* W1h   = (ushort*)(ws + base + 115712);
    ushort* W1l   = (ushort*)(ws + base + 148480);
    ushort* W2h   = (ushort*)(ws + base + 181248);  // 32768 *2B
    ushort* W2l   = (ushort*)(ws + base + 246784);
    float4* Wc0   = (float4*)(ws + base + 312320);  // 128 *16B

    wt4all_kernel<<<13, 256, 0, stream>>>(s1w0, W4s10, s1w1, W4s11, s1w2, W4s12);
    wpack2_kernel<<<257, 256, 0, stream>>>(s2w0, s2b0, s2w1, s2w2,
                                           W0h, W0l, W1h, W1l, W2h, W2l, Wc0);

    // Stage 1
    fps_kernel<4096, 512, 256, true><<<32, 256, 0, stream>>>(xyz, l1_xyz);
    bq_kernel<4096, 32, true, 1024><<<1024, 1024, 0, stream>>>(
        (float)(0.2 * 0.2), xyz, l1_xyz, gidx1, 512);
    {
        dim3 g(256, 32);
        mlp1_kernel<<<g, 256, 0, stream>>>(xyz, l1_xyz, gidx1,
            W4s10, s1b0, W4s11, s1b1, W4s12, s1b2, l1p);
    }

    // Stage 2
    fps_kernel<512, 128, 64, false><<<32, 64, 0, stream>>>(l1_xyz, l2_xyz);
    bq_kernel<512, 64, false, 1024><<<256, 1024, 0, stream>>>(
        (float)(0.4 * 0.4), l1_xyz, l2_xyz, gidx2, 128);
    mlp2_kernel<<<4096, 256, 0, stream>>>(l1_xyz, l1p, l2_xyz, gidx2,
        W0h, W0l, Wc0, W1h, W1l, s2b1, W2h, W2l, s2b2, X3);

    // Stage 3 (group-all MLP as GEMMs over 4096 rows)
    {
        dim3 g1(64, 4);  gemm_kernel<true><<<g1, 256, 0, stream>>>(X3, s3w0, s3b0, Y1, 4096, 259, 256);
        dim3 g2(64, 8);  gemm_kernel<true><<<g2, 256, 0, stream>>>(Y1, s3w1, s3b1, Y2, 4096, 256, 512);
        dim3 g3(64, 16); gemm_kernel<true><<<g3, 256, 0, stream>>>(Y2, s3w2, s3b2, Y3, 4096, 512, 1024);
    }
    max128_kernel<<<128, 256, 0, stream>>>(Y3, feat);

    // FC head
    {
        dim3 g1(1, 8); gemm_kernel<true><<<g1, 256, 0, stream>>>(feat, f1w, f1b, fb1, 32, 1024, 512);
        dim3 g2(1, 4); gemm_kernel<true><<<g2, 256, 0, stream>>>(fb1, f2w, f2b, fb2, 32, 512, 256);
        dim3 g3(1, 1); gemm_kernel<false><<<g3, 256, 0, stream>>>(fb2, f3w, f3b, (float*)d_out, 32, 256, 6);
    }
    (void)in_sizes; (void)n_in; (void)out_size; (void)ws_size;
}

// Round 8
// 1073.179 us; speedup vs baseline: 2.2888x; 1.2389x over previous
//
#include <hip/hip_runtime.h>
#include <hip/hip_bf16.h>

// ---------------------------------------------------------------------------
// PointNet++ critic forward. B=32, N=4096.
// R8: MFMA bf16-split (3-pass hi/lo) extended to mlp1 (layers 1-2) and the
// stage-3 GEMMs (no-LDS gemm_mfma; gemm3 fuses the 128-row max). mlp2 writes
// X3 at stride 288 (zero-padded) so gemm1 runs 9 clean ksteps. FC stays fp32.
// ---------------------------------------------------------------------------

typedef __attribute__((ext_vector_type(8))) short short8;
typedef __attribute__((ext_vector_type(4))) float f32x4;
union SV8 { short8 v; ushort u[8]; };

__device__ __forceinline__ ushort f2bf(float x) {
    unsigned u = __float_as_uint(x);
    unsigned r = (u + 0x7fffu + ((u >> 16) & 1u)) >> 16;   // RNE
    return (ushort)r;
}
__device__ __forceinline__ float bf2f(ushort h) {
    return __uint_as_float(((unsigned)h) << 16);
}

// ======================= DPP wave64 max-reduce (u64) =======================
template<int CTRL>
__device__ __forceinline__ unsigned long long dpp_mov_u64(unsigned long long x) {
    const int lo = (int)(unsigned)(x & 0xffffffffull);
    const int hi = (int)(unsigned)(x >> 32);
    const int nlo = __builtin_amdgcn_update_dpp(lo, lo, CTRL, 0xf, 0xf, false);
    const int nhi = __builtin_amdgcn_update_dpp(hi, hi, CTRL, 0xf, 0xf, false);
    return ((unsigned long long)(unsigned)nhi << 32) | (unsigned)nlo;
}

__device__ __forceinline__ unsigned long long wave_max_u64(unsigned long long x) {
    unsigned long long y;
    y = dpp_mov_u64<0x111>(x); if (y > x) x = y;   // row_shr:1
    y = dpp_mov_u64<0x112>(x); if (y > x) x = y;   // row_shr:2
    y = dpp_mov_u64<0x114>(x); if (y > x) x = y;   // row_shr:4
    y = dpp_mov_u64<0x118>(x); if (y > x) x = y;   // row_shr:8
    y = dpp_mov_u64<0x142>(x); if (y > x) x = y;   // row_bcast:15
    y = dpp_mov_u64<0x143>(x); if (y > x) x = y;   // row_bcast:31
    return x;
}

// ============================ FPS ==========================================
template<int N, int S, int NT, bool CHW>
__global__ __launch_bounds__(NT)
void fps_kernel(const float* __restrict__ xyz, float* __restrict__ new_xyz) {
    constexpr int P  = N / NT;
    constexpr int NW = NT / 64;
    __shared__ __align__(16) float4 sxyz[N];
    __shared__ __align__(16) unsigned long long rv[2][NW > 1 ? NW : 2];
    const int b = blockIdx.x, t = threadIdx.x;
    float px[P], py[P], pz[P], dist[P];
    if (CHW) {
        const float* base = xyz + (size_t)b * 3 * N;
        #pragma unroll
        for (int p = 0; p < P; ++p) {
            const int i = p * NT + t;
            px[p] = base[i]; py[p] = base[N + i]; pz[p] = base[2 * N + i];
            sxyz[i] = make_float4(px[p], py[p], pz[p], 0.0f);
        }
    } else {
        const float* base = xyz + (size_t)b * N * 3;
        #pragma unroll
        for (int p = 0; p < P; ++p) {
            const int i = p * NT + t;
            px[p] = base[i*3]; py[p] = base[i*3+1]; pz[p] = base[i*3+2];
            sxyz[i] = make_float4(px[p], py[p], pz[p], 0.0f);
        }
    }
    #pragma unroll
    for (int p = 0; p < P; ++p) dist[p] = 1e10f;
    __syncthreads();
    int far = 0;
    float* out = new_xyz + (size_t)b * S * 3;
    for (int j = 0; j < S; ++j) {
        const float4 cen = sxyz[far];            // broadcast b128
        if (t == 0) { out[j*3+0] = cen.x; out[j*3+1] = cen.y; out[j*3+2] = cen.z; }
        float bv = -1.0f; int bi = 0;
        #pragma unroll
        for (int p = 0; p < P; ++p) {
            const int i = p * NT + t;
            const float dx = px[p] - cen.x, dy = py[p] - cen.y, dz = pz[p] - cen.z;
            // match reference rounding exactly: no FMA contraction
            const float d = __fadd_rn(__fadd_rn(__fmul_rn(dx, dx), __fmul_rn(dy, dy)), __fmul_rn(dz, dz));
            const float nd = fminf(dist[p], d);
            dist[p] = nd;
            if (nd > bv) { bv = nd; bi = i; }    // strict > keeps smallest i
        }
        unsigned long long pk =
            ((unsigned long long)__float_as_uint(bv) << 32) | (unsigned)(N - 1 - bi);
        pk = wave_max_u64(pk);
        if constexpr (NW > 1) {
            const int sl = j & 1;
            if ((t & 63) == 63) rv[sl][t >> 6] = pk;
            __syncthreads();
            unsigned long long best = rv[sl][0];
            #pragma unroll
            for (int w = 1; w < NW; ++w) { const unsigned long long v = rv[sl][w]; if (v > best) best = v; }
            far = N - 1 - (int)(best & 0xffffffffull);
        } else {
            far = N - 1 - __builtin_amdgcn_readlane((int)(pk & 0xffffffffull), 63);
        }
    }
}

// ============================ Ball query ===================================
template<int N, int NS, bool CHW, int NT>
__global__ __launch_bounds__(NT)
void bq_kernel(float r2, const float* __restrict__ xyz, const float* __restrict__ cen,
               int* __restrict__ gidx, int S) {
    constexpr int WPB = NT / 64;
    __shared__ __align__(16) float4 sp[N];
    const int t = threadIdx.x, lane = t & 63, w = t >> 6;
    const int cen0 = blockIdx.x * WPB;
    const int b = cen0 / S;                     // WPB divides S -> same batch
    if (CHW) {
        const float* base = xyz + (size_t)b * 3 * N;
        for (int i = t; i < N; i += NT)
            sp[i] = make_float4(base[i], base[N + i], base[2 * N + i], 0.0f);
    } else {
        const float* base = xyz + (size_t)b * N * 3;
        for (int i = t; i < N; i += NT)
            sp[i] = make_float4(base[i*3], base[i*3+1], base[i*3+2], 0.0f);
    }
    __syncthreads();
    const int wid = cen0 + w;
    const float cx = cen[(size_t)wid*3+0], cy = cen[(size_t)wid*3+1], cz = cen[(size_t)wid*3+2];
    int* out = gidx + (size_t)wid * NS;
    int cnt = 0, first = -1;
    for (int b0 = 0; b0 < N; b0 += 64) {
        const float4 p = sp[b0 + lane];
        const float dx = p.x - cx, dy = p.y - cy, dz = p.z - cz;
        const float d = __fadd_rn(__fadd_rn(__fmul_rn(dx, dx), __fmul_rn(dy, dy)), __fmul_rn(dz, dz));
        const bool in = (d <= r2);
        const unsigned long long m = __ballot(in);
        if (first < 0 && m != 0ull) first = b0 + __ffsll((unsigned long long)m) - 1;
        const int pos = cnt + (int)__popcll(m & ((1ull << lane) - 1ull));
        if (in && pos < NS) out[pos] = b0 + lane;
        cnt += (int)__popcll(m);
        if (cnt >= NS) break;
    }
    if (cnt < NS)
        for (int k = cnt + lane; k < NS; k += 64) out[k] = first;
}

// ==================== generic weight split + tile pack =====================
// layout: idx = ((ks*OTILES + ot)*64 + lane)*8 + j ; o = ot*16 + (lane&15),
// c = ks*32 + (lane>>4)*8 + j ; zero-pad c >= Ktot.
__device__ __forceinline__ void packg(const float* __restrict__ src,
                                      ushort* __restrict__ dh, ushort* __restrict__ dl,
                                      int Ktot, int otiles, int idx) {
    const int j = idx & 7, lane = (idx >> 3) & 63;
    const int ot = (idx >> 9) % otiles;
    const int ks = idx / (512 * otiles);
    const int m = lane & 15, q = lane >> 4;
    const int o = ot * 16 + m, c = ks * 32 + q * 8 + j;
    const float v = (c < Ktot) ? src[(size_t)o * Ktot + c] : 0.0f;
    const ushort h = f2bf(v);
    dh[idx] = h;
    dl[idx] = f2bf(v - bf2f(h));
}

__global__ __launch_bounds__(256)
void prep_kernel(const float* s1w0, const float* s1b0, float4* Wc1,
                 const float* s1w1, ushort* M1W1h, ushort* M1W1l,
                 const float* s1w2, ushort* M1W2h, ushort* M1W2l,
                 const float* s3w0, ushort* S3W0h, ushort* S3W0l,
                 const float* s3w1, ushort* S3W1h, ushort* S3W1l,
                 const float* s3w2, ushort* S3W2h, ushort* S3W2l) {
    int i = blockIdx.x * 256 + threadIdx.x;
    if (i < 64)     { Wc1[i] = make_float4(s1w0[i*3], s1w0[i*3+1], s1w0[i*3+2], s1b0[i]); return; }  i -= 64;
    if (i < 4096)   { packg(s1w1, M1W1h, M1W1l,  64,  4, i); return; }   i -= 4096;
    if (i < 8192)   { packg(s1w2, M1W2h, M1W2l,  64,  8, i); return; }   i -= 8192;
    if (i < 73728)  { packg(s3w0, S3W0h, S3W0l, 259, 16, i); return; }   i -= 73728;
    if (i < 131072) { packg(s3w1, S3W1h, S3W1l, 256, 32, i); return; }   i -= 131072;
    if (i < 524288) { packg(s3w2, S3W2h, S3W2l, 512, 64, i); return; }
}

// ==================== mlp2 weight split + tile pack (R7) ===================
__global__ __launch_bounds__(256)
void wpack2_kernel(const float* __restrict__ w0, const float* __restrict__ b0,
                   const float* __restrict__ w1, const float* __restrict__ w2,
                   ushort* __restrict__ W0h, ushort* __restrict__ W0l,
                   ushort* __restrict__ W1h, ushort* __restrict__ W1l,
                   ushort* __restrict__ W2h, ushort* __restrict__ W2l,
                   float4* __restrict__ Wc0) {
    int i = blockIdx.x * 256 + threadIdx.x;
    if (i < 65536) {
        const float* src; ushort *dh, *dl; int idx, NOTM, K, cofs;
        if (i < 16384)      { src = w0; dh = W0h; dl = W0l; idx = i;        NOTM = 7;  K = 131; cofs = 3; }
        else if (i < 32768) { src = w1; dh = W1h; dl = W1l; idx = i-16384;  NOTM = 7;  K = 128; cofs = 0; }
        else                { src = w2; dh = W2h; dl = W2l; idx = i-32768;  NOTM = 15; K = 128; cofs = 0; }
        const int j = idx & 7, lane = (idx >> 3) & 63;
        const int ot = (idx >> 9) & NOTM, ks = idx >> (NOTM == 7 ? 12 : 13);
        const int m = lane & 15, q = lane >> 4;
        const int o = ot * 16 + m, c = cofs + ks * 32 + q * 8 + j;
        const float v = src[(size_t)o * K + c];
        const ushort h = f2bf(v);
        dh[idx] = h;
        dl[idx] = f2bf(v - bf2f(h));
    } else if (i < 65664) {
        const int o = i - 65536;
        Wc0[o] = make_float4(w0[(size_t)o*131+0], w0[(size_t)o*131+1], w0[(size_t)o*131+2], b0[o]);
    }
}

// ============================ MLP stage 1 (MFMA) ===========================
// grid (256, 32): 2 s (64 rows) per block, 4 waves; all LDS bands wave-private.
__global__ __launch_bounds__(256)
void mlp1_kernel(const float* __restrict__ xyz, const float* __restrict__ l1xyz,
                 const int* __restrict__ gidx, const float4* __restrict__ Wc1,
                 const ushort* __restrict__ W1h, const ushort* __restrict__ W1l,
                 const float* __restrict__ b1,
                 const ushort* __restrict__ W2h, const ushort* __restrict__ W2l,
                 const float* __restrict__ b2,
                 float* __restrict__ l1p) {
    __shared__ __align__(16) float bufA[64 * 68];   // h0, later max-partials
    __shared__ __align__(16) float bufB[64 * 68];   // g (first 256), later h1
    const int t = threadIdx.x, b = blockIdx.y, s0 = blockIdx.x * 2;
    {   // gather (wave-private rows, but barrier kept for safety)
        const int n = t >> 2, c = t & 3;
        const int s = s0 + (n >> 5);
        const int gi = gidx[((size_t)b * 512 + s) * 32 + (n & 31)];
        float v = 0.0f;
        if (c < 3) v = xyz[(size_t)b * 3 * 4096 + c * 4096 + gi] - l1xyz[((size_t)b * 512 + s) * 3 + c];
        bufB[n * 4 + c] = v;
    }
    __syncthreads();
    {   // layer0: 3 -> 64, exact fp32
        const int o = t & 63, ng = t >> 6;
        const float4 wc = Wc1[o];
        #pragma unroll
        for (int r = 0; r < 16; ++r) {
            const int n = ng * 16 + r;
            const float z = wc.w + wc.x * bufB[n*4] + wc.y * bufB[n*4+1] + wc.z * bufB[n*4+2];
            bufA[n * 68 + o] = fmaxf(z, 0.0f);
        }
    }
    const int lane = t & 63, wv = t >> 6;
    const int m = lane & 15, q = lane >> 4;
    const int rowA = wv * 16 + m;
    // layer1: 64 -> 64 (2 ksteps, 4 otiles)  [wave-private h0 band: no barrier]
    f32x4 acc1[4];
    #pragma unroll
    for (int ot = 0; ot < 4; ++ot)
        #pragma unroll
        for (int r = 0; r < 4; ++r) acc1[ot][r] = 0.0f;
    #pragma unroll
    for (int ks = 0; ks < 2; ++ks) {
        float xv[8];
        *(float4*)&xv[0] = *(const float4*)&bufA[rowA * 68 + ks * 32 + q * 8];
        *(float4*)&xv[4] = *(const float4*)&bufA[rowA * 68 + ks * 32 + q * 8 + 4];
        SV8 ah, al;
        #pragma unroll
        for (int j = 0; j < 8; ++j) { ah.u[j] = f2bf(xv[j]); al.u[j] = f2bf(xv[j] - bf2f(ah.u[j])); }
        #pragma unroll
        for (int ot = 0; ot < 4; ++ot) {
            SV8 bh, bl;
            bh.v = *(const short8*)(W1h + (size_t)((ks * 4 + ot) * 64 + lane) * 8);
            bl.v = *(const short8*)(W1l + (size_t)((ks * 4 + ot) * 64 + lane) * 8);
            acc1[ot] = __builtin_amdgcn_mfma_f32_16x16x32_bf16(ah.v, bh.v, acc1[ot], 0, 0, 0);
            acc1[ot] = __builtin_amdgcn_mfma_f32_16x16x32_bf16(al.v, bh.v, acc1[ot], 0, 0, 0);
            acc1[ot] = __builtin_amdgcn_mfma_f32_16x16x32_bf16(ah.v, bl.v, acc1[ot], 0, 0, 0);
        }
    }
    #pragma unroll
    for (int ot = 0; ot < 4; ++ot) {
        const float bb = b1[ot * 16 + m];
        #pragma unroll
        for (int r = 0; r < 4; ++r)
            bufB[(wv * 16 + q * 4 + r) * 68 + ot * 16 + m] = fmaxf(acc1[ot][r] + bb, 0.0f);
    }
    // layer2: 64 -> 128 (2 ksteps, 8 otiles) + per-wave max  [wave-private]
    f32x4 acc2[8];
    #pragma unroll
    for (int ot = 0; ot < 8; ++ot)
        #pragma unroll
        for (int r = 0; r < 4; ++r) acc2[ot][r] = 0.0f;
    #pragma unroll
    for (int ks = 0; ks < 2; ++ks) {
        float xv[8];
        *(float4*)&xv[0] = *(const float4*)&bufB[rowA * 68 + ks * 32 + q * 8];
        *(float4*)&xv[4] = *(const float4*)&bufB[rowA * 68 + ks * 32 + q * 8 + 4];
        SV8 ah, al;
        #pragma unroll
        for (int j = 0; j < 8; ++j) { ah.u[j] = f2bf(xv[j]); al.u[j] = f2bf(xv[j] - bf2f(ah.u[j])); }
        #pragma unroll
        for (int ot = 0; ot < 8; ++ot) {
            SV8 bh, bl;
            bh.v = *(const short8*)(W2h + (size_t)((ks * 8 + ot) * 64 + lane) * 8);
            bl.v = *(const short8*)(W2l + (size_t)((ks * 8 + ot) * 64 + lane) * 8);
            acc2[ot] = __builtin_amdgcn_mfma_f32_16x16x32_bf16(ah.v, bh.v, acc2[ot], 0, 0, 0);
            acc2[ot] = __builtin_amdgcn_mfma_f32_16x16x32_bf16(al.v, bh.v, acc2[ot], 0, 0, 0);
            acc2[ot] = __builtin_amdgcn_mfma_f32_16x16x32_bf16(ah.v, bl.v, acc2[ot], 0, 0, 0);
        }
    }
    __syncthreads();   // bufA reads (layer1) complete everywhere; reuse for partials
    #pragma unroll
    for (int ot = 0; ot < 8; ++ot) {
        const float bb = b2[ot * 16 + m];
        float mx = 0.0f;
        #pragma unroll
        for (int r = 0; r < 4; ++r) mx = fmaxf(mx, acc2[ot][r] + bb);
        bufA[(wv * 4 + q) * 128 + ot * 16 + m] = mx;
    }
    __syncthreads();
    {   // rows 0..7 = s0, 8..15 = s1
        const int half = t >> 7, o = t & 127;
        float v = bufA[(half * 8) * 128 + o];
        #pragma unroll
        for (int rr = 1; rr < 8; ++rr) v = fmaxf(v, bufA[(half * 8 + rr) * 128 + o]);
        l1p[((size_t)b * 512 + s0 + half) * 128 + o] = v;
    }
}

// ============================ MLP stage 2 (MFMA, R7) =======================
__global__ __launch_bounds__(256)
void mlp2_kernel(const float* __restrict__ l1xyz, const float* __restrict__ l1p,
                 const float* __restrict__ l2xyz, const int* __restrict__ gidx,
                 const ushort* __restrict__ W0h, const ushort* __restrict__ W0l,
                 const float4* __restrict__ Wc0,
                 const ushort* __restrict__ W1h, const ushort* __restrict__ W1l,
                 const float* __restrict__ b1,
                 const ushort* __restrict__ W2h, const ushort* __restrict__ W2l,
                 const float* __restrict__ b2,
                 float* __restrict__ X3) {
    __shared__ __align__(16) float Abuf[64 * 132];   // x / h2
    __shared__ __align__(16) float Bbuf[64 * 132];   // h1 / max-partials
    __shared__ int sg[64];
    const int t = threadIdx.x, bs = blockIdx.x, b = bs >> 7;
    if (t < 64) sg[t] = gidx[(size_t)bs * 64 + t];
    if (t < 3)  X3[(size_t)bs * 288 + t] = l2xyz[(size_t)bs * 3 + t];   // raw coords
    if (t >= 64 && t < 93) X3[(size_t)bs * 288 + 259 + (t - 64)] = 0.0f;  // zero pad
    __syncthreads();
    for (int i = t; i < 64 * 32; i += 256) {
        const int n = i >> 5, cc = i & 31;
        *(float4*)&Abuf[n * 132 + cc * 4] =
            *(const float4*)&l1p[((size_t)b * 512 + sg[n]) * 128 + cc * 4];
    }
    if (t < 192) {
        const int n = t / 3, c = t % 3;
        Abuf[n * 132 + 128 + c] =
            l1xyz[((size_t)b * 512 + sg[n]) * 3 + c] - l2xyz[(size_t)bs * 3 + c];
    }
    __syncthreads();
    const int lane = t & 63, wv = t >> 6;
    const int m = lane & 15, q = lane >> 4;
    const int rowA = wv * 16 + m;

    // layer 0: feats (K=128) MFMA + coords/bias epilogue
    f32x4 acc0[8];
    #pragma unroll
    for (int ot = 0; ot < 8; ++ot)
        #pragma unroll
        for (int r = 0; r < 4; ++r) acc0[ot][r] = 0.0f;
    #pragma unroll
    for (int ks = 0; ks < 4; ++ks) {
        float xv[8];
        *(float4*)&xv[0] = *(const float4*)&Abuf[rowA * 132 + ks * 32 + q * 8];
        *(float4*)&xv[4] = *(const float4*)&Abuf[rowA * 132 + ks * 32 + q * 8 + 4];
        SV8 ah, al;
        #pragma unroll
        for (int j = 0; j < 8; ++j) { ah.u[j] = f2bf(xv[j]); al.u[j] = f2bf(xv[j] - bf2f(ah.u[j])); }
        #pragma unroll
        for (int ot = 0; ot < 8; ++ot) {
            SV8 bh, bl;
            bh.v = *(const short8*)(W0h + (size_t)((ks * 8 + ot) * 64 + lane) * 8);
            bl.v = *(const short8*)(W0l + (size_t)((ks * 8 + ot) * 64 + lane) * 8);
            acc0[ot] = __builtin_amdgcn_mfma_f32_16x16x32_bf16(ah.v, bh.v, acc0[ot], 0, 0, 0);
            acc0[ot] = __builtin_amdgcn_mfma_f32_16x16x32_bf16(al.v, bh.v, acc0[ot], 0, 0, 0);
            acc0[ot] = __builtin_amdgcn_mfma_f32_16x16x32_bf16(ah.v, bl.v, acc0[ot], 0, 0, 0);
        }
    }
    float crd[4][3];
    #pragma unroll
    for (int r = 0; r < 4; ++r) {
        const int n = wv * 16 + q * 4 + r;
        crd[r][0] = Abuf[n * 132 + 128];
        crd[r][1] = Abuf[n * 132 + 129];
        crd[r][2] = Abuf[n * 132 + 130];
    }
    #pragma unroll
    for (int ot = 0; ot < 8; ++ot) {
        const float4 wc = Wc0[ot * 16 + m];
        #pragma unroll
        for (int r = 0; r < 4; ++r) {
            const float v = acc0[ot][r] + wc.w + wc.x * crd[r][0] + wc.y * crd[r][1] + wc.z * crd[r][2];
            Bbuf[(wv * 16 + q * 4 + r) * 132 + ot * 16 + m] = fmaxf(v, 0.0f);
        }
    }
    __syncthreads();

    // layer 1: 128 -> 128
    f32x4 acc1[8];
    #pragma unroll
    for (int ot = 0; ot < 8; ++ot)
        #pragma unroll
        for (int r = 0; r < 4; ++r) acc1[ot][r] = 0.0f;
    #pragma unroll
    for (int ks = 0; ks < 4; ++ks) {
        float xv[8];
        *(float4*)&xv[0] = *(const float4*)&Bbuf[rowA * 132 + ks * 32 + q * 8];
        *(float4*)&xv[4] = *(const float4*)&Bbuf[rowA * 132 + ks * 32 + q * 8 + 4];
        SV8 ah, al;
        #pragma unroll
        for (int j = 0; j < 8; ++j) { ah.u[j] = f2bf(xv[j]); al.u[j] = f2bf(xv[j] - bf2f(ah.u[j])); }
        #pragma unroll
        for (int ot = 0; ot < 8; ++ot) {
            SV8 bh, bl;
            bh.v = *(const short8*)(W1h + (size_t)((ks * 8 + ot) * 64 + lane) * 8);
            bl.v = *(const short8*)(W1l + (size_t)((ks * 8 + ot) * 64 + lane) * 8);
            acc1[ot] = __builtin_amdgcn_mfma_f32_16x16x32_bf16(ah.v, bh.v, acc1[ot], 0, 0, 0);
            acc1[ot] = __builtin_amdgcn_mfma_f32_16x16x32_bf16(al.v, bh.v, acc1[ot], 0, 0, 0);
            acc1[ot] = __builtin_amdgcn_mfma_f32_16x16x32_bf16(ah.v, bl.v, acc1[ot], 0, 0, 0);
        }
    }
    __syncthreads();
    #pragma unroll
    for (int ot = 0; ot < 8; ++ot) {
        const float bb = b1[ot * 16 + m];
        #pragma unroll
        for (int r = 0; r < 4; ++r)
            Abuf[(wv * 16 + q * 4 + r) * 132 + ot * 16 + m] = fmaxf(acc1[ot][r] + bb, 0.0f);
    }
    __syncthreads();

    // layer 2: 128 -> 256, relu+max
    f32x4 acc2[16];
    #pragma unroll
    for (int ot = 0; ot < 16; ++ot)
        #pragma unroll
        for (int r = 0; r < 4; ++r) acc2[ot][r] = 0.0f;
    #pragma unroll
    for (int ks = 0; ks < 4; ++ks) {
        float xv[8];
        *(float4*)&xv[0] = *(const float4*)&Abuf[rowA * 132 + ks * 32 + q * 8];
        *(float4*)&xv[4] = *(const float4*)&Abuf[rowA * 132 + ks * 32 + q * 8 + 4];
        SV8 ah, al;
        #pragma unroll
        for (int j = 0; j < 8; ++j) { ah.u[j] = f2bf(xv[j]); al.u[j] = f2bf(xv[j] - bf2f(ah.u[j])); }
        #pragma unroll
        for (int ot = 0; ot < 16; ++ot) {
            SV8 bh, bl;
            bh.v = *(const short8*)(W2h + (size_t)((ks * 16 + ot) * 64 + lane) * 8);
            bl.v = *(const short8*)(W2l + (size_t)((ks * 16 + ot) * 64 + lane) * 8);
            acc2[ot] = __builtin_amdgcn_mfma_f32_16x16x32_bf16(ah.v, bh.v, acc2[ot], 0, 0, 0);
            acc2[ot] = __builtin_amdgcn_mfma_f32_16x16x32_bf16(al.v, bh.v, acc2[ot], 0, 0, 0);
            acc2[ot] = __builtin_amdgcn_mfma_f32_16x16x32_bf16(ah.v, bl.v, acc2[ot], 0, 0, 0);
        }
    }
    __syncthreads();
    #pragma unroll
    for (int ot = 0; ot < 16; ++ot) {
        const float bb = b2[ot * 16 + m];
        float mx = 0.0f;
        #pragma unroll
        for (int r = 0; r < 4; ++r) mx = fmaxf(mx, acc2[ot][r] + bb);
        Bbuf[(wv * 4 + q) * 256 + ot * 16 + m] = mx;
    }
    __syncthreads();
    {
        float v = Bbuf[t];
        #pragma unroll
        for (int rr = 1; rr < 16; ++rr) v = fmaxf(v, Bbuf[rr * 256 + t]);
        X3[(size_t)bs * 288 + 3 + t] = v;
    }
}

// ===================== stage-3 GEMM via MFMA (no LDS A) ====================
// grid (M/64, O/64). Wave wv: A rows blockIdx.x*64+wv*16+{m}; 4 otiles.
// MAXOUT: fused relu+max over the block's 64 rows -> P[blockIdx.x][O].
template<int KSTEPS, bool MAXOUT>
__global__ __launch_bounds__(256)
void gemm_mfma_kernel(const float* __restrict__ A, int AS,
                      const ushort* __restrict__ Wh, const ushort* __restrict__ Wl,
                      const float* __restrict__ bias, float* __restrict__ C, int O) {
    __shared__ float part[16][64];
    const int t = threadIdx.x, lane = t & 63, wv = t >> 6;
    const int m = lane & 15, q = lane >> 4;
    const int rowA = blockIdx.x * 64 + wv * 16 + m;
    const int bo = blockIdx.y, OT = O >> 4;
    f32x4 acc[4];
    #pragma unroll
    for (int ot = 0; ot < 4; ++ot)
        #pragma unroll
        for (int r = 0; r < 4; ++r) acc[ot][r] = 0.0f;
    for (int ks = 0; ks < KSTEPS; ++ks) {
        float xv[8];
        *(float4*)&xv[0] = *(const float4*)&A[(size_t)rowA * AS + ks * 32 + q * 8];
        *(float4*)&xv[4] = *(const float4*)&A[(size_t)rowA * AS + ks * 32 + q * 8 + 4];
        SV8 ah, al;
        #pragma unroll
        for (int j = 0; j < 8; ++j) { ah.u[j] = f2bf(xv[j]); al.u[j] = f2bf(xv[j] - bf2f(ah.u[j])); }
        #pragma unroll
        for (int ot = 0; ot < 4; ++ot) {
            const size_t wb = (size_t)((ks * OT + bo * 4 + ot) * 64 + lane) * 8;
            SV8 bh, bl;
            bh.v = *(const short8*)(Wh + wb);
            bl.v = *(const short8*)(Wl + wb);
            acc[ot] = __builtin_amdgcn_mfma_f32_16x16x32_bf16(ah.v, bh.v, acc[ot], 0, 0, 0);
            acc[ot] = __builtin_amdgcn_mfma_f32_16x16x32_bf16(al.v, bh.v, acc[ot], 0, 0, 0);
            acc[ot] = __builtin_amdgcn_mfma_f32_16x16x32_bf16(ah.v, bl.v, acc[ot], 0, 0, 0);
        }
    }
    if (!MAXOUT) {
        #pragma unroll
        for (int ot = 0; ot < 4; ++ot) {
            const int col = (bo * 4 + ot) * 16 + m;
            const float bb = bias[col];
            #pragma unroll
            for (int r = 0; r < 4; ++r) {
                const int row = blockIdx.x * 64 + wv * 16 + q * 4 + r;
                C[(size_t)row * O + col] = fmaxf(acc[ot][r] + bb, 0.0f);
            }
        }
    } else {
        #pragma unroll
        for (int ot = 0; ot < 4; ++ot) {
            const int col = (bo * 4 + ot) * 16 + m;
            const float bb = bias[col];
            float mx = 0.0f;
            #pragma unroll
            for (int r = 0; r < 4; ++r) mx = fmaxf(mx, acc[ot][r] + bb);
            part[wv * 4 + q][ot * 16 + m] = mx;
        }
        __syncthreads();
        if (t < 64) {
            float v = part[0][t];
            #pragma unroll
            for (int rr = 1; rr < 16; ++rr) v = fmaxf(v, part[rr][t]);
            C[(size_t)blockIdx.x * O + bo * 64 + t] = v;
        }
    }
}

// ============================ Generic fp32 GEMM (FC head) ==================
template<bool RELU>
__global__ __launch_bounds__(256)
void gemm_kernel(const float* __restrict__ A, const float* __restrict__ W,
                 const float* __restrict__ bias, float* __restrict__ C,
                 int M, int K, int O) {
    __shared__ __align__(16) float At[32*68];
    __shared__ __align__(16) float Wt[32*68];
    const int t = threadIdx.x;
    const int mtile = blockIdx.x * 64, otile = blockIdx.y * 64;
    const int tx = t & 15, ty = t >> 4;
    float acc[4][4];
    #pragma unroll
    for (int i = 0; i < 4; ++i)
        #pragma unroll
        for (int j = 0; j < 4; ++j) acc[i][j] = 0.0f;
    const int kk = t & 31, r0 = t >> 5;
    for (int k0 = 0; k0 < K; k0 += 32) {
        #pragma unroll
        for (int rr = 0; rr < 8; ++rr) {
            const int row = r0 + rr * 8;
            const int m = mtile + row, o = otile + row, k = k0 + kk;
            At[kk*68 + row] = (m < M && k < K) ? A[(size_t)m*K + k] : 0.0f;
            Wt[kk*68 + row] = (o < O && k < K) ? W[(size_t)o*K + k] : 0.0f;
        }
        __syncthreads();
        #pragma unroll
        for (int k2 = 0; k2 < 32; ++k2) {
            const float4 av = *(const float4*)&At[k2*68 + tx*4];
            const float4 wv = *(const float4*)&Wt[k2*68 + ty*4];
            const float a[4] = {av.x, av.y, av.z, av.w};
            const float w[4] = {wv.x, wv.y, wv.z, wv.w};
            #pragma unroll
            for (int i = 0; i < 4; ++i)
                #pragma unroll
                for (int j = 0; j < 4; ++j) acc[i][j] += a[i] * w[j];
        }
        __syncthreads();
    }
    #pragma unroll
    for (int i = 0; i < 4; ++i) {
        const int m = mtile + tx*4 + i;
        if (m >= M) continue;
        #pragma unroll
        for (int j = 0; j < 4; ++j) {
            const int o = otile + ty*4 + j;
            if (o >= O) continue;
            float v = acc[i][j] + bias[o];
            if (RELU) v = fmaxf(v, 0.0f);
            C[(size_t)m*O + o] = v;
        }
    }
}

// ============================ final max (P3 -> feat) =======================
__global__ __launch_bounds__(256)
void maxfin_kernel(const float* __restrict__ P3, float* __restrict__ feat) {
    const int idx = blockIdx.x * 256 + threadIdx.x;  // 32*1024
    const int b = idx >> 10, o = idx & 1023;
    feat[idx] = fmaxf(P3[(size_t)(2*b) * 1024 + o], P3[(size_t)(2*b+1) * 1024 + o]);
}

// ============================ launch =======================================
extern "C" void kernel_launch(void* const* d_in, const int* in_sizes, int n_in,
                              void* d_out, int out_size, void* d_ws, size_t ws_size,
                              hipStream_t stream) {
    const float* xyz  = (const float*)d_in[0];
    const float* s1w0 = (const float*)d_in[1];  const float* s1b0 = (const float*)d_in[2];
    const float* s1w1 = (const float*)d_in[3];  const float* s1b1 = (const float*)d_in[4];
    const float* s1w2 = (const float*)d_in[5];  const float* s1b2 = (const float*)d_in[6];
    const float* s2w0 = (const float*)d_in[7];  const float* s2b0 = (const float*)d_in[8];
    const float* s2w1 = (const float*)d_in[9];  const float* s2b1 = (const float*)d_in[10];
    const float* s2w2 = (const float*)d_in[11]; const float* s2b2 = (const float*)d_in[12];
    const float* s3w0 = (const float*)d_in[13]; const float* s3b0 = (const float*)d_in[14];
    const float* s3w1 = (const float*)d_in[15]; const float* s3b1 = (const float*)d_in[16];
    const float* s3w2 = (const float*)d_in[17]; const float* s3b2 = (const float*)d_in[18];
    const float* f1w  = (const float*)d_in[19]; const float* f1b  = (const float*)d_in[20];
    const float* f2w  = (const float*)d_in[21]; const float* f2b  = (const float*)d_in[22];
    const float* f3w  = (const float*)d_in[23]; const float* f3b  = (const float*)d_in[24];

    char* ws = (char*)d_ws;
    float* l1_xyz = (float*)(ws + 0);              // 32*512*3
    int*   gidx1  = (int*)  (ws + 196608);         // 32*512*32
    float* l1p    = (float*)(ws + 2293760);        // 32*512*128
    float* l2_xyz = (float*)(ws + 10682368);       // 32*128*3
    int*   gidx2  = (int*)  (ws + 10731520);       // 32*128*64
    float* X3p    = (float*)(ws + 11780096);       // 4096*288 (zero-padded)
    const size_t PK = 16498688;                    // pack region
    float4* Wc1   = (float4*)(ws + PK + 0);
    ushort* M1W1h = (ushort*)(ws + PK + 1024);
    ushort* M1W1l = (ushort*)(ws + PK + 9216);
    ushort* M1W2h = (ushort*)(ws + PK + 17408);
    ushort* M1W2l = (ushort*)(ws + PK + 33792);
    ushort* W0h   = (ushort*)(ws + PK + 50176);
    ushort* W0l   = (ushort*)(ws + PK + 82944);
    ushort* W1h   = (ushort*)(ws + PK + 115712);
    ushort* W1l   = (ushort*)(ws + PK + 148480);
    ushort* W2h   = (ushort*)(ws + PK + 181248);
    ushort* W2l   = (ushort*)(ws + PK + 246784);
    float4* Wc0   = (float4*)(ws + PK + 312320);
    ushort* S3W0h = (ushort*)(ws + PK + 314368);
    ushort* S3W0l = (ushort*)(ws + PK + 461824);
    ushort* S3W1h = (ushort*)(ws + PK + 609280);
    ushort* S3W1l = (ushort*)(ws + PK + 871424);
    ushort* S3W2h = (ushort*)(ws + PK + 1133568);
    ushort* S3W2l = (ushort*)(ws + PK + 2182144);
    float* Y1   = (float*)(ws + 19729408);         // 4096*256
    float* Y2   = (float*)(ws + 23923712);         // 4096*512
    float* P3   = (float*)(ws + 32312320);         // 64*1024 partial maxima
    float* feat = (float*)(ws + 32574464);         // 32*1024
    float* fb1  = (float*)(ws + 32705536);         // 32*512
    float* fb2  = (float*)(ws + 32771072);         // 32*256

    prep_kernel<<<2897, 256, 0, stream>>>(s1w0, s1b0, Wc1,
        s1w1, M1W1h, M1W1l, s1w2, M1W2h, M1W2l,
        s3w0, S3W0h, S3W0l, s3w1, S3W1h, S3W1l, s3w2, S3W2h, S3W2l);
    wpack2_kernel<<<257, 256, 0, stream>>>(s2w0, s2b0, s2w1, s2w2,
                                           W0h, W0l, W1h, W1l, W2h, W2l, Wc0);

    // Stage 1
    fps_kernel<4096, 512, 256, true><<<32, 256, 0, stream>>>(xyz, l1_xyz);
    bq_kernel<4096, 32, true, 1024><<<1024, 1024, 0, stream>>>(
        (float)(0.2 * 0.2), xyz, l1_xyz, gidx1, 512);
    {
        dim3 g(256, 32);
        mlp1_kernel<<<g, 256, 0, stream>>>(xyz, l1_xyz, gidx1,
            Wc1, M1W1h, M1W1l, s1b1, M1W2h, M1W2l, s1b2, l1p);
    }

    // Stage 2
    fps_kernel<512, 128, 64, false><<<32, 64, 0, stream>>>(l1_xyz, l2_xyz);
    bq_kernel<512, 64, false, 1024><<<256, 1024, 0, stream>>>(
        (float)(0.4 * 0.4), l1_xyz, l2_xyz, gidx2, 128);
    mlp2_kernel<<<4096, 256, 0, stream>>>(l1_xyz, l1p, l2_xyz, gidx2,
        W0h, W0l, Wc0, W1h, W1l, s2b1, W2h, W2l, s2b2, X3p);

    // Stage 3 (MFMA GEMMs; gemm3 fuses the 128-row max into P3)
    {
        dim3 g1(64, 4);
        gemm_mfma_kernel<9,  false><<<g1, 256, 0, stream>>>(X3p, 288, S3W0h, S3W0l, s3b0, Y1, 256);
        dim3 g2(64, 8);
        gemm_mfma_kernel<8,  false><<<g2, 256, 0, stream>>>(Y1, 256, S3W1h, S3W1l, s3b1, Y2, 512);
        dim3 g3(64, 16);
        gemm_mfma_kernel<16, true ><<<g3, 256, 0, stream>>>(Y2, 512, S3W2h, S3W2l, s3b2, P3, 1024);
    }
    maxfin_kernel<<<128, 256, 0, stream>>>(P3, feat);

    // FC head (fp32)
    {
        dim3 g1(1, 8); gemm_kernel<true><<<g1, 256, 0, stream>>>(feat, f1w, f1b, fb1, 32, 1024, 512);
        dim3 g2(1, 4); gemm_kernel<true><<<g2, 256, 0, stream>>>(fb1, f2w, f2b, fb2, 32, 512, 256);
        dim3 g3(1, 1); gemm_kernel<false><<<g3, 256, 0, stream>>>(fb2, f3w, f3b, (float*)d_out, 32, 256, 6);
    }
    (void)in_sizes; (void)n_in; (void)out_size; (void)ws_size;
}